// Round 1
// baseline (1466.783 us; speedup 1.0000x reference)
//
#include <hip/hip_runtime.h>
#include <cfloat>

#define NEG_SLOPE 0.2f
#define BN_EPS 1e-5f
#define EDGES 1310720   // 16*4096*20
#define INV_M (1.0f / 1310720.0f)

// ---------------- K1: KNN (block per (b,n) row) ----------------
__global__ __launch_bounds__(256) void k1_knn(const float* __restrict__ x, int* __restrict__ idxo) {
  int b = blockIdx.x >> 12;
  int n = blockIdx.x & 4095;
  __shared__ float negd[4096];
  __shared__ float rv[4];
  __shared__ int   ri[4];
  __shared__ int   bwin;
  const float* xb = x + b * 12288;
  int t = threadIdx.x;
  float xn0 = xb[n], xn1 = xb[4096 + n], xn2 = xb[8192 + n];
  float xxn = xn0 * xn0 + xn1 * xn1 + xn2 * xn2;
  float v = -FLT_MAX; int mi = 1 << 30;
  for (int i = 0; i < 16; i++) {
    int m = i * 256 + t;
    float a0 = xb[m], a1 = xb[4096 + m], a2 = xb[8192 + m];
    float inner = a0 * xn0 + a1 * xn1 + a2 * xn2;
    float xxm = a0 * a0 + a1 * a1 + a2 * a2;
    float nd = (2.0f * inner - xxn) - xxm;   // reference formula (negated distance)
    negd[m] = nd;
    if (nd > v) { v = nd; mi = m; }          // strict > keeps smallest index on tie
  }
  __syncthreads();
  int outbase = blockIdx.x * 20;
  for (int j = 0; j < 20; j++) {
    float vv = v; int vm = mi;
    for (int off = 32; off > 0; off >>= 1) {
      float ov = __shfl_down(vv, off);
      int   om = __shfl_down(vm, off);
      if (ov > vv || (ov == vv && om < vm)) { vv = ov; vm = om; }
    }
    if ((t & 63) == 0) { rv[t >> 6] = vv; ri[t >> 6] = vm; }
    __syncthreads();
    if (t == 0) {
      float bv = rv[0]; int bm = ri[0];
      for (int w = 1; w < 4; w++)
        if (rv[w] > bv || (rv[w] == bv && ri[w] < bm)) { bv = rv[w]; bm = ri[w]; }
      idxo[outbase + j] = bm;
      negd[bm] = -FLT_MAX;
      bwin = bm;
    }
    __syncthreads();
    if (mi == bwin) {   // only the owner of the removed candidate rescans
      v = -FLT_MAX; mi = 1 << 30;
      for (int i = 0; i < 16; i++) {
        int m = i * 256 + t;
        float nd = negd[m];
        if (nd > v) { v = nd; mi = m; }
      }
    }
  }
}

// ---------------- K2: accumulate E[e] (6) and E[e e^T] (21) over all edges ----------------
__global__ __launch_bounds__(256) void k2_moments(const float* __restrict__ x,
                                                  const int* __restrict__ idxi,
                                                  float* __restrict__ stat) {
  float acc[27];
  #pragma unroll
  for (int i = 0; i < 27; i++) acc[i] = 0.f;
  int stride = gridDim.x * blockDim.x;
  for (int e = blockIdx.x * blockDim.x + threadIdx.x; e < EDGES; e += stride) {
    int P = e / 20;
    int b = P >> 12;
    int n = P & 4095;
    int m = idxi[e];
    const float* xb = x + b * 12288;
    float xn0 = xb[n], xn1 = xb[4096 + n], xn2 = xb[8192 + n];
    float ev[6];
    ev[0] = xb[m] - xn0; ev[1] = xb[4096 + m] - xn1; ev[2] = xb[8192 + m] - xn2;
    ev[3] = xn0; ev[4] = xn1; ev[5] = xn2;
    int p = 6;
    #pragma unroll
    for (int i2 = 0; i2 < 6; i2++) {
      acc[i2] += ev[i2];
      #pragma unroll
      for (int j2 = i2; j2 < 6; j2++) { acc[p] = fmaf(ev[i2], ev[j2], acc[p]); p++; }
    }
  }
  #pragma unroll
  for (int i = 0; i < 27; i++) {
    float s = acc[i];
    for (int off = 32; off > 0; off >>= 1) s += __shfl_down(s, off);
    acc[i] = s;
  }
  __shared__ float red[4][27];
  int w = threadIdx.x >> 6, lane = threadIdx.x & 63;
  if (lane == 0) {
    #pragma unroll
    for (int i = 0; i < 27; i++) red[w][i] = acc[i];
  }
  __syncthreads();
  if (threadIdx.x < 27) {
    float s = red[0][threadIdx.x] + red[1][threadIdx.x] + red[2][threadIdx.x] + red[3][threadIdx.x];
    atomicAdd(&stat[threadIdx.x], s);
  }
}

// ---------------- K3: finalize BN1 coefficients (1 block, 64 threads) ----------------
__global__ void k3_fin1(const float* __restrict__ stat, const float* __restrict__ W0,
                        const float* __restrict__ g0, const float* __restrict__ b0,
                        float* __restrict__ a1o, float* __restrict__ b1o) {
  int c = threadIdx.x;
  float w[6];
  #pragma unroll
  for (int i = 0; i < 6; i++) w[i] = W0[c * 6 + i];
  float mean = 0.f;
  #pragma unroll
  for (int i = 0; i < 6; i++) mean += w[i] * stat[i];
  mean *= INV_M;
  float e2 = 0.f;
  int p = 6;
  #pragma unroll
  for (int i = 0; i < 6; i++) {
    #pragma unroll
    for (int j = i; j < 6; j++) {
      float f = w[i] * w[j] * stat[p]; p++;
      e2 += (i == j) ? f : 2.f * f;
    }
  }
  e2 *= INV_M;
  float var = e2 - mean * mean;
  float a = g0[c] * rsqrtf(var + BN_EPS);
  a1o[c] = a;
  b1o[c] = b0[c] - mean * a;
}

// ---------------- K4: conv1+BN1+LReLU -> conv2, stats2 partials + per-point max/min ----------------
__global__ __launch_bounds__(256) void k4_main(const float* __restrict__ x, const int* __restrict__ idxi,
                                               const float* __restrict__ W0, const float* __restrict__ W1,
                                               const float* __restrict__ a1, const float* __restrict__ b1e,
                                               float* __restrict__ psum,
                                               float* __restrict__ maxb, float* __restrict__ minb) {
  __shared__ float hbuf[4][64];
  int lane = threadIdx.x & 63;
  int wv = threadIdx.x >> 6;
  int wgid = blockIdx.x * 4 + wv;            // 8192 waves total
  float w0r[6];
  #pragma unroll
  for (int i = 0; i < 6; i++) w0r[i] = W0[lane * 6 + i];
  float w1r[64];
  #pragma unroll
  for (int i = 0; i < 64; i++) w1r[i] = W1[lane * 64 + i];
  float a1c = a1[lane], b1c = b1e[lane];
  float s2 = 0.f, sq2 = 0.f;
  for (int it = 0; it < 8; it++) {
    int P = wgid * 8 + it;                   // point id in [0,65536)
    int b = P >> 12, n = P & 4095;
    const float* xb = x + b * 12288;
    float xn0 = xb[n], xn1 = xb[4096 + n], xn2 = xb[8192 + n];
    float mx = -FLT_MAX, mn = FLT_MAX;
    const int* ip = idxi + P * 20;
    for (int j = 0; j < 20; j++) {
      int m = ip[j];
      float e0 = xb[m] - xn0, e1 = xb[4096 + m] - xn1, e2 = xb[8192 + m] - xn2;
      float h = w0r[0] * e0 + w0r[1] * e1 + w0r[2] * e2
              + w0r[3] * xn0 + w0r[4] * xn1 + w0r[5] * xn2;
      float z = a1c * h + b1c;
      float hn = z >= 0.f ? z : NEG_SLOPE * z;
      hbuf[wv][lane] = hn;                   // wave-private LDS row; in-wave DS ordering
      __builtin_amdgcn_wave_barrier();
      float acc = 0.f;
      const float4* h4 = (const float4*)hbuf[wv];
      #pragma unroll
      for (int c4 = 0; c4 < 16; c4++) {
        float4 hv = h4[c4];                  // broadcast read (all lanes same addr)
        acc = fmaf(w1r[4 * c4 + 0], hv.x, acc);
        acc = fmaf(w1r[4 * c4 + 1], hv.y, acc);
        acc = fmaf(w1r[4 * c4 + 2], hv.z, acc);
        acc = fmaf(w1r[4 * c4 + 3], hv.w, acc);
      }
      __builtin_amdgcn_wave_barrier();
      s2 += acc; sq2 = fmaf(acc, acc, sq2);
      mx = fmaxf(mx, acc); mn = fminf(mn, acc);
    }
    maxb[P * 64 + lane] = mx;
    minb[P * 64 + lane] = mn;
  }
  psum[lane * 8192 + wgid] = s2;             // stat-major partials [128][8192]
  psum[(64 + lane) * 8192 + wgid] = sq2;
}

// ---------------- K4b: reduce stats2 partials (128 blocks, one per stat) ----------------
__global__ __launch_bounds__(256) void k4b_red(const float* __restrict__ psum, float* __restrict__ s2) {
  int c = blockIdx.x;
  const float* p = psum + c * 8192;
  float s = 0.f;
  for (int i = threadIdx.x; i < 8192; i += 256) s += p[i];
  for (int off = 32; off > 0; off >>= 1) s += __shfl_down(s, off);
  __shared__ float red[4];
  if ((threadIdx.x & 63) == 0) red[threadIdx.x >> 6] = s;
  __syncthreads();
  if (threadIdx.x == 0) s2[c] = red[0] + red[1] + red[2] + red[3];
}

// ---------------- K5: BN2+LReLU epilogue with LDS transpose ----------------
__global__ __launch_bounds__(256) void k5_out(const float* __restrict__ maxb, const float* __restrict__ minb,
                                              const float* __restrict__ s2, const float* __restrict__ g1,
                                              const float* __restrict__ b1, float* __restrict__ out) {
  __shared__ float T[64][65];
  __shared__ float a2s[64], b2s[64];
  int blk = blockIdx.x;
  int b = blk >> 6;
  int n0 = (blk & 63) << 6;
  int t = threadIdx.x;
  if (t < 64) {
    float mean = s2[t] * INV_M;
    float var = s2[64 + t] * INV_M - mean * mean;
    float a = g1[t] * rsqrtf(var + BN_EPS);
    a2s[t] = a;
    b2s[t] = b1[t] - mean * a;
  }
  __syncthreads();
  #pragma unroll
  for (int i = 0; i < 16; i++) {
    int lin = i * 256 + t;
    int r = lin >> 6;      // n offset within tile
    int c = lin & 63;      // channel
    float a = a2s[c];
    int P = (b << 12) + n0 + r;
    float v = (a >= 0.f) ? maxb[P * 64 + c] : minb[P * 64 + c];  // monotonicity trick
    float z = a * v + b2s[c];
    T[c][r] = z >= 0.f ? z : NEG_SLOPE * z;
  }
  __syncthreads();
  #pragma unroll
  for (int i = 0; i < 16; i++) {
    int lin = i * 256 + t;
    int c = lin >> 6;
    int nn = lin & 63;
    out[(b * 64 + c) * 4096 + n0 + nn] = T[c][nn];
  }
}

extern "C" void kernel_launch(void* const* d_in, const int* in_sizes, int n_in,
                              void* d_out, int out_size, void* d_ws, size_t ws_size,
                              hipStream_t stream) {
  const float* x  = (const float*)d_in[0];
  const float* W0 = (const float*)d_in[1];
  const float* g0 = (const float*)d_in[2];
  const float* b0 = (const float*)d_in[3];
  const float* W1 = (const float*)d_in[4];
  const float* g1 = (const float*)d_in[5];
  const float* b1 = (const float*)d_in[6];
  float* out = (float*)d_out;
  char* ws = (char*)d_ws;

  // ws layout (bytes)
  int*   idx  = (int*)(ws + 0);                              // 5,242,880 B
  float* stat = (float*)(ws + 5242880);                      // 27 floats (zeroed)
  float* a1   = (float*)(ws + 5242880 + 512);                // 64 floats
  float* b1e  = (float*)(ws + 5242880 + 768);                // 64 floats
  float* s2   = (float*)(ws + 5242880 + 1024);               // 128 floats
  float* part = (float*)(ws + 5242880 + 1536);               // 4 MB: [128][8192]
  float* maxb = (float*)(ws + 5242880 + 1536 + 4194304);     // 16 MB
  float* minb = maxb + 4194304;                              // 16 MB

  hipMemsetAsync(stat, 0, 128, stream);
  k1_knn    <<<65536, 256, 0, stream>>>(x, idx);
  k2_moments<<<1024, 256, 0, stream>>>(x, idx, stat);
  k3_fin1   <<<1, 64, 0, stream>>>(stat, W0, g0, b0, a1, b1e);
  k4_main   <<<2048, 256, 0, stream>>>(x, idx, W0, W1, a1, b1e, part, maxb, minb);
  k4b_red   <<<128, 256, 0, stream>>>(part, s2);
  k5_out    <<<1024, 256, 0, stream>>>(maxb, minb, s2, g1, b1, out);
}

// Round 2
// 917.237 us; speedup vs baseline: 1.5991x; 1.5991x over previous
//
#include <hip/hip_runtime.h>
#include <cfloat>

#define NEG_SLOPE 0.2f
#define BN_EPS 1e-5f
#define EDGES 1310720   // 16*4096*20
#define INV_M (1.0f / 1310720.0f)

// ---------------- K1: KNN — one wave per query, barrier-free selection ----------------
// grid: 1024 blocks = 16 batches x 64 blocks; block = 4 waves; each wave: 16 queries.
__global__ __launch_bounds__(256) void k1_knn(const float* __restrict__ x, int* __restrict__ idxo) {
  __shared__ float xs[3][4096];            // 48 KB x-tile for this batch
  int b   = blockIdx.x >> 6;
  int blk = blockIdx.x & 63;
  const float4* xb4 = (const float4*)(x + b * 12288);
  float4* xs4 = (float4*)xs;
  for (int i = threadIdx.x; i < 3072; i += 256) xs4[i] = xb4[i];
  __syncthreads();

  int wv = threadIdx.x >> 6;
  int lane = threadIdx.x & 63;
  int wave_id = blk * 4 + wv;              // 0..255 within batch

  for (int q = 0; q < 16; q++) {
    int n = wave_id * 16 + q;              // query point
    float xn0 = xs[0][n], xn1 = xs[1][n], xn2 = xs[2][n];   // broadcast reads
    float xxn = xn0 * xn0 + xn1 * xn1 + xn2 * xn2;

    // per-lane sorted top-4 of this lane's 64-candidate column (m = j*64+lane)
    float v0 = -FLT_MAX, v1 = -FLT_MAX, v2 = -FLT_MAX, v3 = -FLT_MAX;
    int   i0 = 0x7fffffff, i1 = 0x7fffffff, i2 = 0x7fffffff, i3 = 0x7fffffff;
    #pragma unroll 4
    for (int j = 0; j < 64; j++) {
      int m = (j << 6) + lane;
      float a0 = xs[0][m], a1 = xs[1][m], a2 = xs[2][m];
      float nd = 2.f * (a0 * xn0 + a1 * xn1 + a2 * xn2) - xxn - (a0 * a0 + a1 * a1 + a2 * a2);
      // branchless sorted insert; ties keep old entry -> ascending index among equals
      bool g0 = nd > v0, g1 = nd > v1, g2 = nd > v2, g3 = nd > v3;
      float nv3 = g3 ? (g2 ? v2 : nd) : v3;  int ni3 = g3 ? (g2 ? i2 : m) : i3;
      float nv2 = g2 ? (g1 ? v1 : nd) : v2;  int ni2 = g2 ? (g1 ? i1 : m) : i2;
      float nv1 = g1 ? (g0 ? v0 : nd) : v1;  int ni1 = g1 ? (g0 ? i0 : m) : i1;
      v0 = g0 ? nd : v0;                     i0 = g0 ? m : i0;
      v1 = nv1; i1 = ni1; v2 = nv2; i2 = ni2; v3 = nv3; i3 = ni3;
    }

    unsigned long long removed = 0ull;     // this lane's removed column slots
    int keep = 0;
    #pragma unroll 1
    for (int r = 0; r < 20; r++) {
      // wave-wide argmax butterfly: (value desc, index asc) — all lanes converge
      float bv = v0; int bi = i0;
      #pragma unroll
      for (int off = 32; off > 0; off >>= 1) {
        float ov = __shfl_xor(bv, off);
        int   oi = __shfl_xor(bi, off);
        if (ov > bv || (ov == bv && oi < bi)) { bv = ov; bi = oi; }
      }
      if (lane == r) keep = bi;            // lane r archives round-r winner
      if ((bi & 63) == lane) {             // owner pops its sorted list
        removed |= 1ull << (bi >> 6);
        v0 = v1; i0 = i1; v1 = v2; i1 = i2; v2 = v3; i2 = i3;
        v3 = -FLT_MAX; i3 = 0x7fffffff;
        if (v0 == -FLT_MAX) {              // list exhausted (rare): rebuild from LDS
          for (int j = 0; j < 64; j++) {
            int m = (j << 6) + lane;
            float a0 = xs[0][m], a1 = xs[1][m], a2 = xs[2][m];
            float nd = 2.f * (a0 * xn0 + a1 * xn1 + a2 * xn2) - xxn - (a0 * a0 + a1 * a1 + a2 * a2);
            if ((removed >> j) & 1ull) nd = -FLT_MAX;
            bool g0 = nd > v0, g1 = nd > v1, g2 = nd > v2, g3 = nd > v3;
            float nv3 = g3 ? (g2 ? v2 : nd) : v3;  int ni3 = g3 ? (g2 ? i2 : m) : i3;
            float nv2 = g2 ? (g1 ? v1 : nd) : v2;  int ni2 = g2 ? (g1 ? i1 : m) : i2;
            float nv1 = g1 ? (g0 ? v0 : nd) : v1;  int ni1 = g1 ? (g0 ? i0 : m) : i1;
            v0 = g0 ? nd : v0;                     i0 = g0 ? m : i0;
            v1 = nv1; i1 = ni1; v2 = nv2; i2 = ni2; v3 = nv3; i3 = ni3;
          }
        }
      }
    }
    if (lane < 20) idxo[((b << 12) + n) * 20 + lane] = keep;
  }
}

// ---------------- K2: accumulate E[e] (6) and E[e e^T] (21) over all edges ----------------
__global__ __launch_bounds__(256) void k2_moments(const float* __restrict__ x,
                                                  const int* __restrict__ idxi,
                                                  float* __restrict__ stat) {
  float acc[27];
  #pragma unroll
  for (int i = 0; i < 27; i++) acc[i] = 0.f;
  int stride = gridDim.x * blockDim.x;
  for (int e = blockIdx.x * blockDim.x + threadIdx.x; e < EDGES; e += stride) {
    int P = e / 20;
    int b = P >> 12;
    int n = P & 4095;
    int m = idxi[e];
    const float* xb = x + b * 12288;
    float xn0 = xb[n], xn1 = xb[4096 + n], xn2 = xb[8192 + n];
    float ev[6];
    ev[0] = xb[m] - xn0; ev[1] = xb[4096 + m] - xn1; ev[2] = xb[8192 + m] - xn2;
    ev[3] = xn0; ev[4] = xn1; ev[5] = xn2;
    int p = 6;
    #pragma unroll
    for (int i2 = 0; i2 < 6; i2++) {
      acc[i2] += ev[i2];
      #pragma unroll
      for (int j2 = i2; j2 < 6; j2++) { acc[p] = fmaf(ev[i2], ev[j2], acc[p]); p++; }
    }
  }
  #pragma unroll
  for (int i = 0; i < 27; i++) {
    float s = acc[i];
    for (int off = 32; off > 0; off >>= 1) s += __shfl_down(s, off);
    acc[i] = s;
  }
  __shared__ float red[4][27];
  int w = threadIdx.x >> 6, lane = threadIdx.x & 63;
  if (lane == 0) {
    #pragma unroll
    for (int i = 0; i < 27; i++) red[w][i] = acc[i];
  }
  __syncthreads();
  if (threadIdx.x < 27) {
    float s = red[0][threadIdx.x] + red[1][threadIdx.x] + red[2][threadIdx.x] + red[3][threadIdx.x];
    atomicAdd(&stat[threadIdx.x], s);
  }
}

// ---------------- K3: finalize BN1 coefficients (1 block, 64 threads) ----------------
__global__ void k3_fin1(const float* __restrict__ stat, const float* __restrict__ W0,
                        const float* __restrict__ g0, const float* __restrict__ b0,
                        float* __restrict__ a1o, float* __restrict__ b1o) {
  int c = threadIdx.x;
  float w[6];
  #pragma unroll
  for (int i = 0; i < 6; i++) w[i] = W0[c * 6 + i];
  float mean = 0.f;
  #pragma unroll
  for (int i = 0; i < 6; i++) mean += w[i] * stat[i];
  mean *= INV_M;
  float e2 = 0.f;
  int p = 6;
  #pragma unroll
  for (int i = 0; i < 6; i++) {
    #pragma unroll
    for (int j = i; j < 6; j++) {
      float f = w[i] * w[j] * stat[p]; p++;
      e2 += (i == j) ? f : 2.f * f;
    }
  }
  e2 *= INV_M;
  float var = e2 - mean * mean;
  float a = g0[c] * rsqrtf(var + BN_EPS);
  a1o[c] = a;
  b1o[c] = b0[c] - mean * a;
}

// ---------------- K4: conv1+BN1+LReLU -> conv2, stats2 partials + per-point max/min ----------------
__global__ __launch_bounds__(256) void k4_main(const float* __restrict__ x, const int* __restrict__ idxi,
                                               const float* __restrict__ W0, const float* __restrict__ W1,
                                               const float* __restrict__ a1, const float* __restrict__ b1e,
                                               float* __restrict__ psum,
                                               float* __restrict__ maxb, float* __restrict__ minb) {
  __shared__ float hbuf[4][64];
  int lane = threadIdx.x & 63;
  int wv = threadIdx.x >> 6;
  int wgid = blockIdx.x * 4 + wv;            // 8192 waves total
  float w0r[6];
  #pragma unroll
  for (int i = 0; i < 6; i++) w0r[i] = W0[lane * 6 + i];
  float w1r[64];
  #pragma unroll
  for (int i = 0; i < 64; i++) w1r[i] = W1[lane * 64 + i];
  float a1c = a1[lane], b1c = b1e[lane];
  float s2 = 0.f, sq2 = 0.f;
  for (int it = 0; it < 8; it++) {
    int P = wgid * 8 + it;                   // point id in [0,65536)
    int b = P >> 12, n = P & 4095;
    const float* xb = x + b * 12288;
    float xn0 = xb[n], xn1 = xb[4096 + n], xn2 = xb[8192 + n];
    float mx = -FLT_MAX, mn = FLT_MAX;
    const int* ip = idxi + P * 20;
    for (int j = 0; j < 20; j++) {
      int m = ip[j];
      float e0 = xb[m] - xn0, e1 = xb[4096 + m] - xn1, e2 = xb[8192 + m] - xn2;
      float h = w0r[0] * e0 + w0r[1] * e1 + w0r[2] * e2
              + w0r[3] * xn0 + w0r[4] * xn1 + w0r[5] * xn2;
      float z = a1c * h + b1c;
      float hn = z >= 0.f ? z : NEG_SLOPE * z;
      hbuf[wv][lane] = hn;                   // wave-private LDS row; in-wave DS ordering
      __builtin_amdgcn_wave_barrier();
      float acc = 0.f;
      const float4* h4 = (const float4*)hbuf[wv];
      #pragma unroll
      for (int c4 = 0; c4 < 16; c4++) {
        float4 hv = h4[c4];                  // broadcast read (all lanes same addr)
        acc = fmaf(w1r[4 * c4 + 0], hv.x, acc);
        acc = fmaf(w1r[4 * c4 + 1], hv.y, acc);
        acc = fmaf(w1r[4 * c4 + 2], hv.z, acc);
        acc = fmaf(w1r[4 * c4 + 3], hv.w, acc);
      }
      __builtin_amdgcn_wave_barrier();
      s2 += acc; sq2 = fmaf(acc, acc, sq2);
      mx = fmaxf(mx, acc); mn = fminf(mn, acc);
    }
    maxb[P * 64 + lane] = mx;
    minb[P * 64 + lane] = mn;
  }
  psum[lane * 8192 + wgid] = s2;             // stat-major partials [128][8192]
  psum[(64 + lane) * 8192 + wgid] = sq2;
}

// ---------------- K4b: reduce stats2 partials (128 blocks, one per stat) ----------------
__global__ __launch_bounds__(256) void k4b_red(const float* __restrict__ psum, float* __restrict__ s2) {
  int c = blockIdx.x;
  const float* p = psum + c * 8192;
  float s = 0.f;
  for (int i = threadIdx.x; i < 8192; i += 256) s += p[i];
  for (int off = 32; off > 0; off >>= 1) s += __shfl_down(s, off);
  __shared__ float red[4];
  if ((threadIdx.x & 63) == 0) red[threadIdx.x >> 6] = s;
  __syncthreads();
  if (threadIdx.x == 0) s2[c] = red[0] + red[1] + red[2] + red[3];
}

// ---------------- K5: BN2+LReLU epilogue with LDS transpose ----------------
__global__ __launch_bounds__(256) void k5_out(const float* __restrict__ maxb, const float* __restrict__ minb,
                                              const float* __restrict__ s2, const float* __restrict__ g1,
                                              const float* __restrict__ b1, float* __restrict__ out) {
  __shared__ float T[64][65];
  __shared__ float a2s[64], b2s[64];
  int blk = blockIdx.x;
  int b = blk >> 6;
  int n0 = (blk & 63) << 6;
  int t = threadIdx.x;
  if (t < 64) {
    float mean = s2[t] * INV_M;
    float var = s2[64 + t] * INV_M - mean * mean;
    float a = g1[t] * rsqrtf(var + BN_EPS);
    a2s[t] = a;
    b2s[t] = b1[t] - mean * a;
  }
  __syncthreads();
  #pragma unroll
  for (int i = 0; i < 16; i++) {
    int lin = i * 256 + t;
    int r = lin >> 6;      // n offset within tile
    int c = lin & 63;      // channel
    float a = a2s[c];
    int P = (b << 12) + n0 + r;
    float v = (a >= 0.f) ? maxb[P * 64 + c] : minb[P * 64 + c];  // monotonicity trick
    float z = a * v + b2s[c];
    T[c][r] = z >= 0.f ? z : NEG_SLOPE * z;
  }
  __syncthreads();
  #pragma unroll
  for (int i = 0; i < 16; i++) {
    int lin = i * 256 + t;
    int c = lin >> 6;
    int nn = lin & 63;
    out[(b * 64 + c) * 4096 + n0 + nn] = T[c][nn];
  }
}

extern "C" void kernel_launch(void* const* d_in, const int* in_sizes, int n_in,
                              void* d_out, int out_size, void* d_ws, size_t ws_size,
                              hipStream_t stream) {
  const float* x  = (const float*)d_in[0];
  const float* W0 = (const float*)d_in[1];
  const float* g0 = (const float*)d_in[2];
  const float* b0 = (const float*)d_in[3];
  const float* W1 = (const float*)d_in[4];
  const float* g1 = (const float*)d_in[5];
  const float* b1 = (const float*)d_in[6];
  float* out = (float*)d_out;
  char* ws = (char*)d_ws;

  // ws layout (bytes)
  int*   idx  = (int*)(ws + 0);                              // 5,242,880 B
  float* stat = (float*)(ws + 5242880);                      // 27 floats (zeroed)
  float* a1   = (float*)(ws + 5242880 + 512);                // 64 floats
  float* b1e  = (float*)(ws + 5242880 + 768);                // 64 floats
  float* s2   = (float*)(ws + 5242880 + 1024);               // 128 floats
  float* part = (float*)(ws + 5242880 + 1536);               // 4 MB: [128][8192]
  float* maxb = (float*)(ws + 5242880 + 1536 + 4194304);     // 16 MB
  float* minb = maxb + 4194304;                              // 16 MB

  hipMemsetAsync(stat, 0, 128, stream);
  k1_knn    <<<1024, 256, 0, stream>>>(x, idx);
  k2_moments<<<1024, 256, 0, stream>>>(x, idx, stat);
  k3_fin1   <<<1, 64, 0, stream>>>(stat, W0, g0, b0, a1, b1e);
  k4_main   <<<2048, 256, 0, stream>>>(x, idx, W0, W1, a1, b1e, part, maxb, minb);
  k4b_red   <<<128, 256, 0, stream>>>(part, s2);
  k5_out    <<<1024, 256, 0, stream>>>(maxb, minb, s2, g1, b1, out);
}

// Round 4
// 794.653 us; speedup vs baseline: 1.8458x; 1.1543x over previous
//
#include <hip/hip_runtime.h>
#include <cfloat>

#define NEG_SLOPE 0.2f
#define BN_EPS 1e-5f
#define EDGES 1310720   // 16*4096*20
#define INV_M (1.0f / 1310720.0f)

// pack (neg-dist value, index) into one u64 key: larger key == (higher value, then smaller index)
__device__ __forceinline__ unsigned long long packkey(float nd, int m) {
  unsigned u = __float_as_uint(nd);
  unsigned key = ((int)u < 0) ? ~u : (u | 0x80000000u);   // monotone float->uint
  return ((unsigned long long)key << 32) | (unsigned)(~m);
}

__device__ __forceinline__ unsigned long long shfl_xor_u64(unsigned long long v, int off) {
  int hi = __shfl_xor((int)(v >> 32), off);
  int lo = __shfl_xor((int)(unsigned)v, off);
  return ((unsigned long long)(unsigned)hi << 32) | (unsigned)lo;
}

// branchless sorted-insert into descending top-3 (keys unique by construction)
__device__ __forceinline__ void ins3(unsigned long long k, unsigned long long& k0,
                                     unsigned long long& k1, unsigned long long& k2) {
  bool g0 = k > k0, g1 = k > k1, g2 = k > k2;
  unsigned long long n2 = g2 ? (g1 ? k1 : k) : k2;
  unsigned long long n1 = g1 ? (g0 ? k0 : k) : k1;
  k0 = g0 ? k : k0;
  k1 = n1; k2 = n2;
}

// ---------------- K1: KNN — one wave per query pair, barrier-free selection ----------------
// grid: 512 blocks = 16 batches x 32 blocks; block = 8 waves; each wave: 8 query pairs.
// Distance MUST use the reference expression shape: 2*(c.q) - xxn - xxm, xxm recomputed
// inline (NOT precomputed/reassociated) — round-3 reassociation flipped a near-tie
// at the k=20 boundary vs the numpy ref (absmax 0.219 > 0.216).
__global__ __launch_bounds__(512) void k1_knn(const float* __restrict__ x, int* __restrict__ idxo) {
  __shared__ float4 xs[4096];              // 64 KB: (x, y, z, pad) per point
  int b   = blockIdx.x >> 5;
  int blk = blockIdx.x & 31;
  const float* xb = x + b * 12288;
  for (int i = threadIdx.x; i < 4096; i += 512) {
    xs[i] = make_float4(xb[i], xb[4096 + i], xb[8192 + i], 0.f);
  }
  __syncthreads();

  int wv = threadIdx.x >> 6;
  int lane = threadIdx.x & 63;
  int wave_id = blk * 8 + wv;              // 0..255 within batch

  #pragma unroll 1
  for (int p = 0; p < 8; p++) {
    int nA = wave_id * 16 + 2 * p;
    int nB = nA + 1;
    float4 qA = xs[nA];                    // broadcast reads
    float4 qB = xs[nB];
    float xxnA = qA.x * qA.x + qA.y * qA.y + qA.z * qA.z;
    float xxnB = qB.x * qB.x + qB.y * qB.y + qB.z * qB.z;

    unsigned long long A0 = 0, A1 = 0, A2 = 0;
    unsigned long long B0 = 0, B1 = 0, B2 = 0;
    #pragma unroll 4
    for (int j = 0; j < 64; j++) {
      int m = (j << 6) + lane;
      float4 c = xs[m];
      float ndA = 2.f * (c.x * qA.x + c.y * qA.y + c.z * qA.z) - xxnA
                - (c.x * c.x + c.y * c.y + c.z * c.z);
      ins3(packkey(ndA, m), A0, A1, A2);
      float ndB = 2.f * (c.x * qB.x + c.y * qB.y + c.z * qB.z) - xxnB
                - (c.x * c.x + c.y * c.y + c.z * c.z);
      ins3(packkey(ndB, m), B0, B1, B2);
    }

    unsigned long long remA = 0ull, remB = 0ull;
    int keepA = 0, keepB = 0;
    #pragma unroll 1
    for (int r = 0; r < 20; r++) {
      unsigned long long wA = A0, wB = B0;
      #pragma unroll
      for (int off = 32; off > 0; off >>= 1) {
        unsigned long long oA = shfl_xor_u64(wA, off);
        unsigned long long oB = shfl_xor_u64(wB, off);
        if (oA > wA) wA = oA;
        if (oB > wB) wB = oB;
      }
      int mA = (int)~(unsigned)wA;         // low32 of key is ~m
      int mB = (int)~(unsigned)wB;
      if (lane == r) { keepA = mA; keepB = mB; }
      if ((mA & 63) == lane) {             // owner pops its sorted list
        remA |= 1ull << (mA >> 6);
        A0 = A1; A1 = A2; A2 = 0;
        if (A0 == 0) {                     // exhausted (rare): rebuild from LDS
          #pragma unroll 1
          for (int j = 0; j < 64; j++) {
            int m = (j << 6) + lane;
            float4 c = xs[m];
            float ndA = 2.f * (c.x * qA.x + c.y * qA.y + c.z * qA.z) - xxnA
                      - (c.x * c.x + c.y * c.y + c.z * c.z);
            unsigned long long k = ((remA >> j) & 1ull) ? 0ull : packkey(ndA, m);
            ins3(k, A0, A1, A2);
          }
        }
      }
      if ((mB & 63) == lane) {
        remB |= 1ull << (mB >> 6);
        B0 = B1; B1 = B2; B2 = 0;
        if (B0 == 0) {
          #pragma unroll 1
          for (int j = 0; j < 64; j++) {
            int m = (j << 6) + lane;
            float4 c = xs[m];
            float ndB = 2.f * (c.x * qB.x + c.y * qB.y + c.z * qB.z) - xxnB
                      - (c.x * c.x + c.y * c.y + c.z * c.z);
            unsigned long long k = ((remB >> j) & 1ull) ? 0ull : packkey(ndB, m);
            ins3(k, B0, B1, B2);
          }
        }
      }
    }
    if (lane < 20) {
      idxo[((b << 12) + nA) * 20 + lane] = keepA;
      idxo[((b << 12) + nB) * 20 + lane] = keepB;
    }
  }
}

// ---------------- K2: accumulate E[e] (6) and E[e e^T] (21) over all edges ----------------
__global__ __launch_bounds__(256) void k2_moments(const float* __restrict__ x,
                                                  const int* __restrict__ idxi,
                                                  float* __restrict__ stat) {
  float acc[27];
  #pragma unroll
  for (int i = 0; i < 27; i++) acc[i] = 0.f;
  int stride = gridDim.x * blockDim.x;
  for (int e = blockIdx.x * blockDim.x + threadIdx.x; e < EDGES; e += stride) {
    int P = e / 20;
    int b = P >> 12;
    int n = P & 4095;
    int m = idxi[e];
    const float* xb = x + b * 12288;
    float xn0 = xb[n], xn1 = xb[4096 + n], xn2 = xb[8192 + n];
    float ev[6];
    ev[0] = xb[m] - xn0; ev[1] = xb[4096 + m] - xn1; ev[2] = xb[8192 + m] - xn2;
    ev[3] = xn0; ev[4] = xn1; ev[5] = xn2;
    int p = 6;
    #pragma unroll
    for (int i2 = 0; i2 < 6; i2++) {
      acc[i2] += ev[i2];
      #pragma unroll
      for (int j2 = i2; j2 < 6; j2++) { acc[p] = fmaf(ev[i2], ev[j2], acc[p]); p++; }
    }
  }
  #pragma unroll
  for (int i = 0; i < 27; i++) {
    float s = acc[i];
    for (int off = 32; off > 0; off >>= 1) s += __shfl_down(s, off);
    acc[i] = s;
  }
  __shared__ float red[4][27];
  int w = threadIdx.x >> 6, lane = threadIdx.x & 63;
  if (lane == 0) {
    #pragma unroll
    for (int i = 0; i < 27; i++) red[w][i] = acc[i];
  }
  __syncthreads();
  if (threadIdx.x < 27) {
    float s = red[0][threadIdx.x] + red[1][threadIdx.x] + red[2][threadIdx.x] + red[3][threadIdx.x];
    atomicAdd(&stat[threadIdx.x], s);
  }
}

// ---------------- K3: finalize BN1 coefficients (1 block, 64 threads) ----------------
__global__ void k3_fin1(const float* __restrict__ stat, const float* __restrict__ W0,
                        const float* __restrict__ g0, const float* __restrict__ b0,
                        float* __restrict__ a1o, float* __restrict__ b1o) {
  int c = threadIdx.x;
  float w[6];
  #pragma unroll
  for (int i = 0; i < 6; i++) w[i] = W0[c * 6 + i];
  float mean = 0.f;
  #pragma unroll
  for (int i = 0; i < 6; i++) mean += w[i] * stat[i];
  mean *= INV_M;
  float e2 = 0.f;
  int p = 6;
  #pragma unroll
  for (int i = 0; i < 6; i++) {
    #pragma unroll
    for (int j = i; j < 6; j++) {
      float f = w[i] * w[j] * stat[p]; p++;
      e2 += (i == j) ? f : 2.f * f;
    }
  }
  e2 *= INV_M;
  float var = e2 - mean * mean;
  float a = g0[c] * rsqrtf(var + BN_EPS);
  a1o[c] = a;
  b1o[c] = b0[c] - mean * a;
}

// ---------------- K4: conv1+BN1+LReLU -> conv2, stats2 partials + per-point max/min ----------------
__global__ __launch_bounds__(256) void k4_main(const float* __restrict__ x, const int* __restrict__ idxi,
                                               const float* __restrict__ W0, const float* __restrict__ W1,
                                               const float* __restrict__ a1, const float* __restrict__ b1e,
                                               float* __restrict__ psum,
                                               float* __restrict__ maxb, float* __restrict__ minb) {
  __shared__ float hbuf[4][64];
  int lane = threadIdx.x & 63;
  int wv = threadIdx.x >> 6;
  int wgid = blockIdx.x * 4 + wv;            // 8192 waves total
  float w0r[6];
  #pragma unroll
  for (int i = 0; i < 6; i++) w0r[i] = W0[lane * 6 + i];
  float w1r[64];
  #pragma unroll
  for (int i = 0; i < 64; i++) w1r[i] = W1[lane * 64 + i];
  float a1c = a1[lane], b1c = b1e[lane];
  float s2 = 0.f, sq2 = 0.f;
  for (int it = 0; it < 8; it++) {
    int P = wgid * 8 + it;                   // point id in [0,65536)
    int b = P >> 12, n = P & 4095;
    const float* xb = x + b * 12288;
    float xn0 = xb[n], xn1 = xb[4096 + n], xn2 = xb[8192 + n];
    float mx = -FLT_MAX, mn = FLT_MAX;
    const int* ip = idxi + P * 20;
    for (int j = 0; j < 20; j++) {
      int m = ip[j];
      float e0 = xb[m] - xn0, e1 = xb[4096 + m] - xn1, e2 = xb[8192 + m] - xn2;
      float h = w0r[0] * e0 + w0r[1] * e1 + w0r[2] * e2
              + w0r[3] * xn0 + w0r[4] * xn1 + w0r[5] * xn2;
      float z = a1c * h + b1c;
      float hn = z >= 0.f ? z : NEG_SLOPE * z;
      hbuf[wv][lane] = hn;                   // wave-private LDS row; in-wave DS ordering
      __builtin_amdgcn_wave_barrier();
      float acc = 0.f;
      const float4* h4 = (const float4*)hbuf[wv];
      #pragma unroll
      for (int c4 = 0; c4 < 16; c4++) {
        float4 hv = h4[c4];                  // broadcast read (all lanes same addr)
        acc = fmaf(w1r[4 * c4 + 0], hv.x, acc);
        acc = fmaf(w1r[4 * c4 + 1], hv.y, acc);
        acc = fmaf(w1r[4 * c4 + 2], hv.z, acc);
        acc = fmaf(w1r[4 * c4 + 3], hv.w, acc);
      }
      __builtin_amdgcn_wave_barrier();
      s2 += acc; sq2 = fmaf(acc, acc, sq2);
      mx = fmaxf(mx, acc); mn = fminf(mn, acc);
    }
    maxb[P * 64 + lane] = mx;
    minb[P * 64 + lane] = mn;
  }
  psum[lane * 8192 + wgid] = s2;             // stat-major partials [128][8192]
  psum[(64 + lane) * 8192 + wgid] = sq2;
}

// ---------------- K4b: reduce stats2 partials (128 blocks, one per stat) ----------------
__global__ __launch_bounds__(256) void k4b_red(const float* __restrict__ psum, float* __restrict__ s2) {
  int c = blockIdx.x;
  const float* p = psum + c * 8192;
  float s = 0.f;
  for (int i = threadIdx.x; i < 8192; i += 256) s += p[i];
  for (int off = 32; off > 0; off >>= 1) s += __shfl_down(s, off);
  __shared__ float red[4];
  if ((threadIdx.x & 63) == 0) red[threadIdx.x >> 6] = s;
  __syncthreads();
  if (threadIdx.x == 0) s2[c] = red[0] + red[1] + red[2] + red[3];
}

// ---------------- K5: BN2+LReLU epilogue with LDS transpose ----------------
__global__ __launch_bounds__(256) void k5_out(const float* __restrict__ maxb, const float* __restrict__ minb,
                                              const float* __restrict__ s2, const float* __restrict__ g1,
                                              const float* __restrict__ b1, float* __restrict__ out) {
  __shared__ float T[64][65];
  __shared__ float a2s[64], b2s[64];
  int blk = blockIdx.x;
  int b = blk >> 6;
  int n0 = (blk & 63) << 6;
  int t = threadIdx.x;
  if (t < 64) {
    float mean = s2[t] * INV_M;
    float var = s2[64 + t] * INV_M - mean * mean;
    float a = g1[t] * rsqrtf(var + BN_EPS);
    a2s[t] = a;
    b2s[t] = b1[t] - mean * a;
  }
  __syncthreads();
  #pragma unroll
  for (int i = 0; i < 16; i++) {
    int lin = i * 256 + t;
    int r = lin >> 6;      // n offset within tile
    int c = lin & 63;      // channel
    float a = a2s[c];
    int P = (b << 12) + n0 + r;
    float v = (a >= 0.f) ? maxb[P * 64 + c] : minb[P * 64 + c];  // monotonicity trick
    float z = a * v + b2s[c];
    T[c][r] = z >= 0.f ? z : NEG_SLOPE * z;
  }
  __syncthreads();
  #pragma unroll
  for (int i = 0; i < 16; i++) {
    int lin = i * 256 + t;
    int c = lin >> 6;
    int nn = lin & 63;
    out[(b * 64 + c) * 4096 + n0 + nn] = T[c][nn];
  }
}

extern "C" void kernel_launch(void* const* d_in, const int* in_sizes, int n_in,
                              void* d_out, int out_size, void* d_ws, size_t ws_size,
                              hipStream_t stream) {
  const float* x  = (const float*)d_in[0];
  const float* W0 = (const float*)d_in[1];
  const float* g0 = (const float*)d_in[2];
  const float* b0 = (const float*)d_in[3];
  const float* W1 = (const float*)d_in[4];
  const float* g1 = (const float*)d_in[5];
  const float* b1 = (const float*)d_in[6];
  float* out = (float*)d_out;
  char* ws = (char*)d_ws;

  // ws layout (bytes)
  int*   idx  = (int*)(ws + 0);                              // 5,242,880 B
  float* stat = (float*)(ws + 5242880);                      // 27 floats (zeroed)
  float* a1   = (float*)(ws + 5242880 + 512);                // 64 floats
  float* b1e  = (float*)(ws + 5242880 + 768);                // 64 floats
  float* s2   = (float*)(ws + 5242880 + 1024);               // 128 floats
  float* part = (float*)(ws + 5242880 + 1536);               // 4 MB: [128][8192]
  float* maxb = (float*)(ws + 5242880 + 1536 + 4194304);     // 16 MB
  float* minb = maxb + 4194304;                              // 16 MB

  hipMemsetAsync(stat, 0, 128, stream);
  k1_knn    <<<512, 512, 0, stream>>>(x, idx);
  k2_moments<<<1024, 256, 0, stream>>>(x, idx, stat);
  k3_fin1   <<<1, 64, 0, stream>>>(stat, W0, g0, b0, a1, b1e);
  k4_main   <<<2048, 256, 0, stream>>>(x, idx, W0, W1, a1, b1e, part, maxb, minb);
  k4b_red   <<<128, 256, 0, stream>>>(part, s2);
  k5_out    <<<1024, 256, 0, stream>>>(maxb, minb, s2, g1, b1, out);
}

// Round 8
// 779.209 us; speedup vs baseline: 1.8824x; 1.0198x over previous
//
#include <hip/hip_runtime.h>
#include <cfloat>

#define NEG_SLOPE 0.2f
#define BN_EPS 1e-5f
#define EDGES 1310720   // 16*4096*20
#define INV_M (1.0f / 1310720.0f)

// Bit-exact replica of the numpy fp32 neg-distance. `#pragma clang fp contract(off)`
// is the ONLY reliable way to stop hipcc's -ffp-contract=fast from fusing these into
// fmas (HIP's __fmul_rn etc. are plain a*b inline fns -> still contractible; round 7
// proved that: identical 0.21875 failure as round 6). With contraction off and
// numpy's sequential order, GPU distances == numpy distances bitwise, so the
// selected neighbor set matches exactly.
__device__ __forceinline__ float sqnorm_np(float c0, float c1, float c2) {
#pragma clang fp contract(off)
  return (c0 * c0 + c1 * c1) + c2 * c2;
}
__device__ __forceinline__ float negdist_np(float c0, float c1, float c2,
                                            float q0, float q1, float q2,
                                            float xxn, float xxm) {
#pragma clang fp contract(off)
  float inner = (c0 * q0 + c1 * q1) + c2 * q2;
  return (2.0f * inner - xxn) - xxm;
}

// pack (neg-dist value, index) into one u64 key: larger key == (higher value, then smaller index)
__device__ __forceinline__ unsigned long long packkey(float nd, int m) {
  unsigned u = __float_as_uint(nd);
  unsigned key = ((int)u < 0) ? ~u : (u | 0x80000000u);   // monotone float->uint
  return ((unsigned long long)key << 32) | (unsigned)(~m);
}

// xor-butterfly shuffle within 32-lane halves: ds_swizzle BitMode pattern (xor<<10)|0x1F
template <int PAT>
__device__ __forceinline__ unsigned long long swz64(unsigned long long v) {
  int hi = __builtin_amdgcn_ds_swizzle((int)(v >> 32), PAT);
  int lo = __builtin_amdgcn_ds_swizzle((int)(unsigned)v, PAT);
  return ((unsigned long long)(unsigned)hi << 32) | (unsigned)lo;
}
// cross-half (lane^32) via bpermute with a precomputed byte address
__device__ __forceinline__ unsigned long long bperm64(int addr, unsigned long long v) {
  int hi = __builtin_amdgcn_ds_bpermute(addr, (int)(v >> 32));
  int lo = __builtin_amdgcn_ds_bpermute(addr, (int)(unsigned)v);
  return ((unsigned long long)(unsigned)hi << 32) | (unsigned)lo;
}
__device__ __forceinline__ unsigned long long maxu64(unsigned long long a, unsigned long long b) {
  return a > b ? a : b;
}

// branchless sorted-insert into descending top-3 (keys unique by construction)
__device__ __forceinline__ void ins3(unsigned long long k, unsigned long long& k0,
                                     unsigned long long& k1, unsigned long long& k2) {
  bool g0 = k > k0, g1 = k > k1, g2 = k > k2;
  unsigned long long n2 = g2 ? (g1 ? k1 : k) : k2;
  unsigned long long n1 = g1 ? (g0 ? k0 : k) : k1;
  k0 = g0 ? k : k0;
  k1 = n1; k2 = n2;
}

// ---------------- K1: KNN — one wave per query pair, barrier-free selection ----------------
// grid: 256 blocks = 16 batches x 16 blocks; block = 16 waves; each wave: 8 query pairs.
// 48 KB LDS + launch_bounds(1024,8) -> 2 blocks/CU = 32 waves/CU.
__global__ __launch_bounds__(1024, 8) void k1_knn(const float* __restrict__ x, int* __restrict__ idxo) {
  __shared__ float xs0[4096], xs1[4096], xs2[4096];   // 48 KB
  int b   = blockIdx.x >> 4;
  int blk = blockIdx.x & 15;
  const float* xb = x + b * 12288;
  for (int i = threadIdx.x; i < 4096; i += 1024) {
    xs0[i] = xb[i];
    xs1[i] = xb[4096 + i];
    xs2[i] = xb[8192 + i];
  }
  __syncthreads();

  int wv = threadIdx.x >> 6;
  int lane = threadIdx.x & 63;
  int wave_id = blk * 16 + wv;             // 0..255 within batch
  int xaddr = ((lane ^ 32) << 2);          // bpermute byte address for the xor-32 stage

  #pragma unroll 1
  for (int p = 0; p < 8; p++) {
    int nA = wave_id * 16 + 2 * p;
    int nB = nA + 1;
    float qA0 = xs0[nA], qA1 = xs1[nA], qA2 = xs2[nA];   // broadcast reads
    float qB0 = xs0[nB], qB1 = xs1[nB], qB2 = xs2[nB];
    float xxnA = sqnorm_np(qA0, qA1, qA2);
    float xxnB = sqnorm_np(qB0, qB1, qB2);

    unsigned long long A0 = 0, A1 = 0, A2 = 0;
    unsigned long long B0 = 0, B1 = 0, B2 = 0;
    #pragma unroll 2
    for (int j = 0; j < 64; j++) {
      int m = (j << 6) + lane;
      float c0 = xs0[m], c1 = xs1[m], c2 = xs2[m];
      float xxm = sqnorm_np(c0, c1, c2);
      float ndA = negdist_np(c0, c1, c2, qA0, qA1, qA2, xxnA, xxm);
      ins3(packkey(ndA, m), A0, A1, A2);
      float ndB = negdist_np(c0, c1, c2, qB0, qB1, qB2, xxnB, xxm);
      ins3(packkey(ndB, m), B0, B1, B2);
    }

    unsigned long long remA = 0ull, remB = 0ull;
    int keepA = 0, keepB = 0;
    #pragma unroll 1
    for (int r = 0; r < 20; r++) {
      unsigned long long wA = A0, wB = B0;
      wA = maxu64(wA, swz64<0x041F>(wA)); wB = maxu64(wB, swz64<0x041F>(wB));  // xor 1
      wA = maxu64(wA, swz64<0x081F>(wA)); wB = maxu64(wB, swz64<0x081F>(wB));  // xor 2
      wA = maxu64(wA, swz64<0x101F>(wA)); wB = maxu64(wB, swz64<0x101F>(wB));  // xor 4
      wA = maxu64(wA, swz64<0x201F>(wA)); wB = maxu64(wB, swz64<0x201F>(wB));  // xor 8
      wA = maxu64(wA, swz64<0x401F>(wA)); wB = maxu64(wB, swz64<0x401F>(wB));  // xor 16
      wA = maxu64(wA, bperm64(xaddr, wA)); wB = maxu64(wB, bperm64(xaddr, wB)); // xor 32

      int mA = (int)~(unsigned)wA;         // low32 of key is ~m
      int mB = (int)~(unsigned)wB;
      if (lane == r) { keepA = mA; keepB = mB; }

      bool ownA = ((mA & 63) == lane);     // branchless pop
      remA |= ownA ? (1ull << (mA >> 6)) : 0ull;
      A0 = ownA ? A1 : A0;
      A1 = ownA ? A2 : A1;
      A2 = ownA ? 0ull : A2;
      if (ownA & (A0 == 0ull)) {           // exhausted (rare): rebuild from LDS
        #pragma unroll 1
        for (int j = 0; j < 64; j++) {
          int m = (j << 6) + lane;
          float c0 = xs0[m], c1 = xs1[m], c2 = xs2[m];
          float xxm = sqnorm_np(c0, c1, c2);
          float ndA = negdist_np(c0, c1, c2, qA0, qA1, qA2, xxnA, xxm);
          unsigned long long k = ((remA >> j) & 1ull) ? 0ull : packkey(ndA, m);
          ins3(k, A0, A1, A2);
        }
      }
      bool ownB = ((mB & 63) == lane);
      remB |= ownB ? (1ull << (mB >> 6)) : 0ull;
      B0 = ownB ? B1 : B0;
      B1 = ownB ? B2 : B1;
      B2 = ownB ? 0ull : B2;
      if (ownB & (B0 == 0ull)) {
        #pragma unroll 1
        for (int j = 0; j < 64; j++) {
          int m = (j << 6) + lane;
          float c0 = xs0[m], c1 = xs1[m], c2 = xs2[m];
          float xxm = sqnorm_np(c0, c1, c2);
          float ndB = negdist_np(c0, c1, c2, qB0, qB1, qB2, xxnB, xxm);
          unsigned long long k = ((remB >> j) & 1ull) ? 0ull : packkey(ndB, m);
          ins3(k, B0, B1, B2);
        }
      }
    }
    if (lane < 20) {
      idxo[((b << 12) + nA) * 20 + lane] = keepA;
      idxo[((b << 12) + nB) * 20 + lane] = keepB;
    }
  }
}

// ---------------- K2: accumulate E[e] (6) and E[e e^T] (21) over all edges ----------------
__global__ __launch_bounds__(256) void k2_moments(const float* __restrict__ x,
                                                  const int* __restrict__ idxi,
                                                  float* __restrict__ stat) {
  float acc[27];
  #pragma unroll
  for (int i = 0; i < 27; i++) acc[i] = 0.f;
  int stride = gridDim.x * blockDim.x;
  for (int e = blockIdx.x * blockDim.x + threadIdx.x; e < EDGES; e += stride) {
    int P = e / 20;
    int b = P >> 12;
    int n = P & 4095;
    int m = idxi[e];
    const float* xb = x + b * 12288;
    float xn0 = xb[n], xn1 = xb[4096 + n], xn2 = xb[8192 + n];
    float ev[6];
    ev[0] = xb[m] - xn0; ev[1] = xb[4096 + m] - xn1; ev[2] = xb[8192 + m] - xn2;
    ev[3] = xn0; ev[4] = xn1; ev[5] = xn2;
    int p = 6;
    #pragma unroll
    for (int i2 = 0; i2 < 6; i2++) {
      acc[i2] += ev[i2];
      #pragma unroll
      for (int j2 = i2; j2 < 6; j2++) { acc[p] = fmaf(ev[i2], ev[j2], acc[p]); p++; }
    }
  }
  #pragma unroll
  for (int i = 0; i < 27; i++) {
    float s = acc[i];
    for (int off = 32; off > 0; off >>= 1) s += __shfl_down(s, off);
    acc[i] = s;
  }
  __shared__ float red[4][27];
  int w = threadIdx.x >> 6, lane = threadIdx.x & 63;
  if (lane == 0) {
    #pragma unroll
    for (int i = 0; i < 27; i++) red[w][i] = acc[i];
  }
  __syncthreads();
  if (threadIdx.x < 27) {
    float s = red[0][threadIdx.x] + red[1][threadIdx.x] + red[2][threadIdx.x] + red[3][threadIdx.x];
    atomicAdd(&stat[threadIdx.x], s);
  }
}

// ---------------- K3: finalize BN1 coefficients (1 block, 64 threads) ----------------
__global__ void k3_fin1(const float* __restrict__ stat, const float* __restrict__ W0,
                        const float* __restrict__ g0, const float* __restrict__ b0,
                        float* __restrict__ a1o, float* __restrict__ b1o) {
  int c = threadIdx.x;
  float w[6];
  #pragma unroll
  for (int i = 0; i < 6; i++) w[i] = W0[c * 6 + i];
  float mean = 0.f;
  #pragma unroll
  for (int i = 0; i < 6; i++) mean += w[i] * stat[i];
  mean *= INV_M;
  float e2 = 0.f;
  int p = 6;
  #pragma unroll
  for (int i = 0; i < 6; i++) {
    #pragma unroll
    for (int j = i; j < 6; j++) {
      float f = w[i] * w[j] * stat[p]; p++;
      e2 += (i == j) ? f : 2.f * f;
    }
  }
  e2 *= INV_M;
  float var = e2 - mean * mean;
  float a = g0[c] * rsqrtf(var + BN_EPS);
  a1o[c] = a;
  b1o[c] = b0[c] - mean * a;
}

// ---------------- K4: conv1+BN1+LReLU -> conv2, stats2 partials + per-point max/min ----------------
__global__ __launch_bounds__(256) void k4_main(const float* __restrict__ x, const int* __restrict__ idxi,
                                               const float* __restrict__ W0, const float* __restrict__ W1,
                                               const float* __restrict__ a1, const float* __restrict__ b1e,
                                               float* __restrict__ psum,
                                               float* __restrict__ maxb, float* __restrict__ minb) {
  __shared__ float hbuf[4][64];
  int lane = threadIdx.x & 63;
  int wv = threadIdx.x >> 6;
  int wgid = blockIdx.x * 4 + wv;            // 8192 waves total
  float w0r[6];
  #pragma unroll
  for (int i = 0; i < 6; i++) w0r[i] = W0[lane * 6 + i];
  float w1r[64];
  #pragma unroll
  for (int i = 0; i < 64; i++) w1r[i] = W1[lane * 64 + i];
  float a1c = a1[lane], b1c = b1e[lane];
  float s2 = 0.f, sq2 = 0.f;
  for (int it = 0; it < 8; it++) {
    int P = wgid * 8 + it;                   // point id in [0,65536)
    int b = P >> 12, n = P & 4095;
    const float* xb = x + b * 12288;
    float xn0 = xb[n], xn1 = xb[4096 + n], xn2 = xb[8192 + n];
    float mx = -FLT_MAX, mn = FLT_MAX;
    const int* ip = idxi + P * 20;
    for (int j = 0; j < 20; j++) {
      int m = ip[j];
      float e0 = xb[m] - xn0, e1 = xb[4096 + m] - xn1, e2 = xb[8192 + m] - xn2;
      float h = w0r[0] * e0 + w0r[1] * e1 + w0r[2] * e2
              + w0r[3] * xn0 + w0r[4] * xn1 + w0r[5] * xn2;
      float z = a1c * h + b1c;
      float hn = z >= 0.f ? z : NEG_SLOPE * z;
      hbuf[wv][lane] = hn;                   // wave-private LDS row; in-wave DS ordering
      __builtin_amdgcn_wave_barrier();
      float acc = 0.f;
      const float4* h4 = (const float4*)hbuf[wv];
      #pragma unroll
      for (int c4 = 0; c4 < 16; c4++) {
        float4 hv = h4[c4];                  // broadcast read (all lanes same addr)
        acc = fmaf(w1r[4 * c4 + 0], hv.x, acc);
        acc = fmaf(w1r[4 * c4 + 1], hv.y, acc);
        acc = fmaf(w1r[4 * c4 + 2], hv.z, acc);
        acc = fmaf(w1r[4 * c4 + 3], hv.w, acc);
      }
      __builtin_amdgcn_wave_barrier();
      s2 += acc; sq2 = fmaf(acc, acc, sq2);
      mx = fmaxf(mx, acc); mn = fminf(mn, acc);
    }
    maxb[P * 64 + lane] = mx;
    minb[P * 64 + lane] = mn;
  }
  psum[lane * 8192 + wgid] = s2;             // stat-major partials [128][8192]
  psum[(64 + lane) * 8192 + wgid] = sq2;
}

// ---------------- K4b: reduce stats2 partials (128 blocks, one per stat) ----------------
__global__ __launch_bounds__(256) void k4b_red(const float* __restrict__ psum, float* __restrict__ s2) {
  int c = blockIdx.x;
  const float* p = psum + c * 8192;
  float s = 0.f;
  for (int i = threadIdx.x; i < 8192; i += 256) s += p[i];
  for (int off = 32; off > 0; off >>= 1) s += __shfl_down(s, off);
  __shared__ float red[4];
  if ((threadIdx.x & 63) == 0) red[threadIdx.x >> 6] = s;
  __syncthreads();
  if (threadIdx.x == 0) s2[c] = red[0] + red[1] + red[2] + red[3];
}

// ---------------- K5: BN2+LReLU epilogue with LDS transpose ----------------
__global__ __launch_bounds__(256) void k5_out(const float* __restrict__ maxb, const float* __restrict__ minb,
                                              const float* __restrict__ s2, const float* __restrict__ g1,
                                              const float* __restrict__ b1, float* __restrict__ out) {
  __shared__ float T[64][65];
  __shared__ float a2s[64], b2s[64];
  int blk = blockIdx.x;
  int b = blk >> 6;
  int n0 = (blk & 63) << 6;
  int t = threadIdx.x;
  if (t < 64) {
    float mean = s2[t] * INV_M;
    float var = s2[64 + t] * INV_M - mean * mean;
    float a = g1[t] * rsqrtf(var + BN_EPS);
    a2s[t] = a;
    b2s[t] = b1[t] - mean * a;
  }
  __syncthreads();
  #pragma unroll
  for (int i = 0; i < 16; i++) {
    int lin = i * 256 + t;
    int r = lin >> 6;      // n offset within tile
    int c = lin & 63;      // channel
    float a = a2s[c];
    int P = (b << 12) + n0 + r;
    float v = (a >= 0.f) ? maxb[P * 64 + c] : minb[P * 64 + c];  // monotonicity trick
    float z = a * v + b2s[c];
    T[c][r] = z >= 0.f ? z : NEG_SLOPE * z;
  }
  __syncthreads();
  #pragma unroll
  for (int i = 0; i < 16; i++) {
    int lin = i * 256 + t;
    int c = lin >> 6;
    int nn = lin & 63;
    out[(b * 64 + c) * 4096 + n0 + nn] = T[c][nn];
  }
}

extern "C" void kernel_launch(void* const* d_in, const int* in_sizes, int n_in,
                              void* d_out, int out_size, void* d_ws, size_t ws_size,
                              hipStream_t stream) {
  const float* x  = (const float*)d_in[0];
  const float* W0 = (const float*)d_in[1];
  const float* g0 = (const float*)d_in[2];
  const float* b0 = (const float*)d_in[3];
  const float* W1 = (const float*)d_in[4];
  const float* g1 = (const float*)d_in[5];
  const float* b1 = (const float*)d_in[6];
  float* out = (float*)d_out;
  char* ws = (char*)d_ws;

  // ws layout (bytes)
  int*   idx  = (int*)(ws + 0);                              // 5,242,880 B
  float* stat = (float*)(ws + 5242880);                      // 27 floats (zeroed)
  float* a1   = (float*)(ws + 5242880 + 512);                // 64 floats
  float* b1e  = (float*)(ws + 5242880 + 768);                // 64 floats
  float* s2   = (float*)(ws + 5242880 + 1024);               // 128 floats
  float* part = (float*)(ws + 5242880 + 1536);               // 4 MB: [128][8192]
  float* maxb = (float*)(ws + 5242880 + 1536 + 4194304);     // 16 MB
  float* minb = maxb + 4194304;                              // 16 MB

  (void)hipMemsetAsync(stat, 0, 128, stream);
  k1_knn    <<<256, 1024, 0, stream>>>(x, idx);
  k2_moments<<<1024, 256, 0, stream>>>(x, idx, stat);
  k3_fin1   <<<1, 64, 0, stream>>>(stat, W0, g0, b0, a1, b1e);
  k4_main   <<<2048, 256, 0, stream>>>(x, idx, W0, W1, a1, b1e, part, maxb, minb);
  k4b_red   <<<128, 256, 0, stream>>>(part, s2);
  k5_out    <<<1024, 256, 0, stream>>>(maxb, minb, s2, g1, b1, out);
}

// Round 9
// 725.247 us; speedup vs baseline: 2.0225x; 1.0744x over previous
//
#include <hip/hip_runtime.h>
#include <cfloat>

#define NEG_SLOPE 0.2f
#define BN_EPS 1e-5f
#define EDGES 1310720   // 16*4096*20
#define INV_M (1.0f / 1310720.0f)

// Bit-exact replica of the numpy fp32 neg-distance. `#pragma clang fp contract(off)`
// is the ONLY reliable way to stop hipcc's -ffp-contract=fast from fusing these into
// fmas (HIP's __fmul_rn etc. are plain a*b inline fns -> still contractible; round 7
// proved that). With contraction off and numpy's sequential order, GPU distances ==
// numpy distances bitwise, so the selected neighbor set matches exactly.
__device__ __forceinline__ float sqnorm_np(float c0, float c1, float c2) {
#pragma clang fp contract(off)
  return (c0 * c0 + c1 * c1) + c2 * c2;
}
__device__ __forceinline__ float negdist_np(float c0, float c1, float c2,
                                            float q0, float q1, float q2,
                                            float xxn, float xxm) {
#pragma clang fp contract(off)
  float inner = (c0 * q0 + c1 * q1) + c2 * q2;
  return (2.0f * inner - xxn) - xxm;
}

// pack (neg-dist value, index) into one u64 key: larger key == (higher value, then smaller index)
__device__ __forceinline__ unsigned long long packkey(float nd, int m) {
  unsigned u = __float_as_uint(nd);
  unsigned key = ((int)u < 0) ? ~u : (u | 0x80000000u);   // monotone float->uint
  return ((unsigned long long)key << 32) | (unsigned)(~m);
}

// xor-butterfly shuffle within 32-lane halves: ds_swizzle BitMode pattern (xor<<10)|0x1F
template <int PAT>
__device__ __forceinline__ unsigned long long swz64(unsigned long long v) {
  int hi = __builtin_amdgcn_ds_swizzle((int)(v >> 32), PAT);
  int lo = __builtin_amdgcn_ds_swizzle((int)(unsigned)v, PAT);
  return ((unsigned long long)(unsigned)hi << 32) | (unsigned)lo;
}
// cross-half (lane^32) via bpermute with a precomputed byte address
__device__ __forceinline__ unsigned long long bperm64(int addr, unsigned long long v) {
  int hi = __builtin_amdgcn_ds_bpermute(addr, (int)(v >> 32));
  int lo = __builtin_amdgcn_ds_bpermute(addr, (int)(unsigned)v);
  return ((unsigned long long)(unsigned)hi << 32) | (unsigned)lo;
}
__device__ __forceinline__ unsigned long long maxu64(unsigned long long a, unsigned long long b) {
  return a > b ? a : b;
}

// branchless sorted-insert into descending top-3 (keys unique by construction)
__device__ __forceinline__ void ins3(unsigned long long k, unsigned long long& k0,
                                     unsigned long long& k1, unsigned long long& k2) {
  bool g0 = k > k0, g1 = k > k1, g2 = k > k2;
  unsigned long long n2 = g2 ? (g1 ? k1 : k) : k2;
  unsigned long long n1 = g1 ? (g0 ? k0 : k) : k1;
  k0 = g0 ? k : k0;
  k1 = n1; k2 = n2;
}

// ---------------- K1: KNN — one wave per query pair, barrier-free selection ----------------
// grid: 512 blocks = 16 batches x 32 blocks; block = 16 waves; each wave: 4 query pairs.
// 48 KB LDS x 2 blocks/CU = 96 KB -> 32 waves/CU (round 8 had 256 blocks = 1 block/CU
// = 16 waves/CU, occupancy-starved at 27.6% with VALUBusy 76%).
__global__ __launch_bounds__(1024, 8) void k1_knn(const float* __restrict__ x, int* __restrict__ idxo) {
  __shared__ float xs0[4096], xs1[4096], xs2[4096];   // 48 KB
  int b   = blockIdx.x >> 5;
  int blk = blockIdx.x & 31;
  const float* xb = x + b * 12288;
  for (int i = threadIdx.x; i < 4096; i += 1024) {
    xs0[i] = xb[i];
    xs1[i] = xb[4096 + i];
    xs2[i] = xb[8192 + i];
  }
  __syncthreads();

  int wv = threadIdx.x >> 6;
  int lane = threadIdx.x & 63;
  int wave_id = blk * 16 + wv;             // 0..511 within batch
  int xaddr = ((lane ^ 32) << 2);          // bpermute byte address for the xor-32 stage

  #pragma unroll 1
  for (int p = 0; p < 4; p++) {
    int nA = wave_id * 8 + 2 * p;
    int nB = nA + 1;
    float qA0 = xs0[nA], qA1 = xs1[nA], qA2 = xs2[nA];   // broadcast reads
    float qB0 = xs0[nB], qB1 = xs1[nB], qB2 = xs2[nB];
    float xxnA = sqnorm_np(qA0, qA1, qA2);
    float xxnB = sqnorm_np(qB0, qB1, qB2);

    unsigned long long A0 = 0, A1 = 0, A2 = 0;
    unsigned long long B0 = 0, B1 = 0, B2 = 0;
    #pragma unroll 2
    for (int j = 0; j < 64; j++) {
      int m = (j << 6) + lane;
      float c0 = xs0[m], c1 = xs1[m], c2 = xs2[m];
      float xxm = sqnorm_np(c0, c1, c2);
      float ndA = negdist_np(c0, c1, c2, qA0, qA1, qA2, xxnA, xxm);
      ins3(packkey(ndA, m), A0, A1, A2);
      float ndB = negdist_np(c0, c1, c2, qB0, qB1, qB2, xxnB, xxm);
      ins3(packkey(ndB, m), B0, B1, B2);
    }

    unsigned long long remA = 0ull, remB = 0ull;
    int keepA = 0, keepB = 0;
    #pragma unroll 1
    for (int r = 0; r < 20; r++) {
      unsigned long long wA = A0, wB = B0;
      wA = maxu64(wA, swz64<0x041F>(wA)); wB = maxu64(wB, swz64<0x041F>(wB));  // xor 1
      wA = maxu64(wA, swz64<0x081F>(wA)); wB = maxu64(wB, swz64<0x081F>(wB));  // xor 2
      wA = maxu64(wA, swz64<0x101F>(wA)); wB = maxu64(wB, swz64<0x101F>(wB));  // xor 4
      wA = maxu64(wA, swz64<0x201F>(wA)); wB = maxu64(wB, swz64<0x201F>(wB));  // xor 8
      wA = maxu64(wA, swz64<0x401F>(wA)); wB = maxu64(wB, swz64<0x401F>(wB));  // xor 16
      wA = maxu64(wA, bperm64(xaddr, wA)); wB = maxu64(wB, bperm64(xaddr, wB)); // xor 32

      int mA = (int)~(unsigned)wA;         // low32 of key is ~m
      int mB = (int)~(unsigned)wB;
      if (lane == r) { keepA = mA; keepB = mB; }

      bool ownA = ((mA & 63) == lane);     // branchless pop
      remA |= ownA ? (1ull << (mA >> 6)) : 0ull;
      A0 = ownA ? A1 : A0;
      A1 = ownA ? A2 : A1;
      A2 = ownA ? 0ull : A2;
      if (ownA & (A0 == 0ull)) {           // exhausted (rare): rebuild from LDS
        #pragma unroll 1
        for (int j = 0; j < 64; j++) {
          int m = (j << 6) + lane;
          float c0 = xs0[m], c1 = xs1[m], c2 = xs2[m];
          float xxm = sqnorm_np(c0, c1, c2);
          float ndA = negdist_np(c0, c1, c2, qA0, qA1, qA2, xxnA, xxm);
          unsigned long long k = ((remA >> j) & 1ull) ? 0ull : packkey(ndA, m);
          ins3(k, A0, A1, A2);
        }
      }
      bool ownB = ((mB & 63) == lane);
      remB |= ownB ? (1ull << (mB >> 6)) : 0ull;
      B0 = ownB ? B1 : B0;
      B1 = ownB ? B2 : B1;
      B2 = ownB ? 0ull : B2;
      if (ownB & (B0 == 0ull)) {
        #pragma unroll 1
        for (int j = 0; j < 64; j++) {
          int m = (j << 6) + lane;
          float c0 = xs0[m], c1 = xs1[m], c2 = xs2[m];
          float xxm = sqnorm_np(c0, c1, c2);
          float ndB = negdist_np(c0, c1, c2, qB0, qB1, qB2, xxnB, xxm);
          unsigned long long k = ((remB >> j) & 1ull) ? 0ull : packkey(ndB, m);
          ins3(k, B0, B1, B2);
        }
      }
    }
    if (lane < 20) {
      idxo[((b << 12) + nA) * 20 + lane] = keepA;
      idxo[((b << 12) + nB) * 20 + lane] = keepB;
    }
  }
}

// ---------------- K2: accumulate E[e] (6) and E[e e^T] (21) over all edges ----------------
__global__ __launch_bounds__(256) void k2_moments(const float* __restrict__ x,
                                                  const int* __restrict__ idxi,
                                                  float* __restrict__ stat) {
  float acc[27];
  #pragma unroll
  for (int i = 0; i < 27; i++) acc[i] = 0.f;
  int stride = gridDim.x * blockDim.x;
  for (int e = blockIdx.x * blockDim.x + threadIdx.x; e < EDGES; e += stride) {
    int P = e / 20;
    int b = P >> 12;
    int n = P & 4095;
    int m = idxi[e];
    const float* xb = x + b * 12288;
    float xn0 = xb[n], xn1 = xb[4096 + n], xn2 = xb[8192 + n];
    float ev[6];
    ev[0] = xb[m] - xn0; ev[1] = xb[4096 + m] - xn1; ev[2] = xb[8192 + m] - xn2;
    ev[3] = xn0; ev[4] = xn1; ev[5] = xn2;
    int p = 6;
    #pragma unroll
    for (int i2 = 0; i2 < 6; i2++) {
      acc[i2] += ev[i2];
      #pragma unroll
      for (int j2 = i2; j2 < 6; j2++) { acc[p] = fmaf(ev[i2], ev[j2], acc[p]); p++; }
    }
  }
  #pragma unroll
  for (int i = 0; i < 27; i++) {
    float s = acc[i];
    for (int off = 32; off > 0; off >>= 1) s += __shfl_down(s, off);
    acc[i] = s;
  }
  __shared__ float red[4][27];
  int w = threadIdx.x >> 6, lane = threadIdx.x & 63;
  if (lane == 0) {
    #pragma unroll
    for (int i = 0; i < 27; i++) red[w][i] = acc[i];
  }
  __syncthreads();
  if (threadIdx.x < 27) {
    float s = red[0][threadIdx.x] + red[1][threadIdx.x] + red[2][threadIdx.x] + red[3][threadIdx.x];
    atomicAdd(&stat[threadIdx.x], s);
  }
}

// ---------------- K3: finalize BN1 coefficients (1 block, 64 threads) ----------------
__global__ void k3_fin1(const float* __restrict__ stat, const float* __restrict__ W0,
                        const float* __restrict__ g0, const float* __restrict__ b0,
                        float* __restrict__ a1o, float* __restrict__ b1o) {
  int c = threadIdx.x;
  float w[6];
  #pragma unroll
  for (int i = 0; i < 6; i++) w[i] = W0[c * 6 + i];
  float mean = 0.f;
  #pragma unroll
  for (int i = 0; i < 6; i++) mean += w[i] * stat[i];
  mean *= INV_M;
  float e2 = 0.f;
  int p = 6;
  #pragma unroll
  for (int i = 0; i < 6; i++) {
    #pragma unroll
    for (int j = i; j < 6; j++) {
      float f = w[i] * w[j] * stat[p]; p++;
      e2 += (i == j) ? f : 2.f * f;
    }
  }
  e2 *= INV_M;
  float var = e2 - mean * mean;
  float a = g0[c] * rsqrtf(var + BN_EPS);
  a1o[c] = a;
  b1o[c] = b0[c] - mean * a;
}

// ---------------- K4: conv1+BN1+LReLU -> conv2, stats2 partials + per-point max/min ----------------
__global__ __launch_bounds__(256) void k4_main(const float* __restrict__ x, const int* __restrict__ idxi,
                                               const float* __restrict__ W0, const float* __restrict__ W1,
                                               const float* __restrict__ a1, const float* __restrict__ b1e,
                                               float* __restrict__ psum,
                                               float* __restrict__ maxb, float* __restrict__ minb) {
  __shared__ float hbuf[4][64];
  int lane = threadIdx.x & 63;
  int wv = threadIdx.x >> 6;
  int wgid = blockIdx.x * 4 + wv;            // 8192 waves total
  float w0r[6];
  #pragma unroll
  for (int i = 0; i < 6; i++) w0r[i] = W0[lane * 6 + i];
  float w1r[64];
  #pragma unroll
  for (int i = 0; i < 64; i++) w1r[i] = W1[lane * 64 + i];
  float a1c = a1[lane], b1c = b1e[lane];
  float s2 = 0.f, sq2 = 0.f;
  for (int it = 0; it < 8; it++) {
    int P = wgid * 8 + it;                   // point id in [0,65536)
    int b = P >> 12, n = P & 4095;
    const float* xb = x + b * 12288;
    float xn0 = xb[n], xn1 = xb[4096 + n], xn2 = xb[8192 + n];
    float mx = -FLT_MAX, mn = FLT_MAX;
    const int* ip = idxi + P * 20;
    for (int j = 0; j < 20; j++) {
      int m = ip[j];
      float e0 = xb[m] - xn0, e1 = xb[4096 + m] - xn1, e2 = xb[8192 + m] - xn2;
      float h = w0r[0] * e0 + w0r[1] * e1 + w0r[2] * e2
              + w0r[3] * xn0 + w0r[4] * xn1 + w0r[5] * xn2;
      float z = a1c * h + b1c;
      float hn = z >= 0.f ? z : NEG_SLOPE * z;
      hbuf[wv][lane] = hn;                   // wave-private LDS row; in-wave DS ordering
      __builtin_amdgcn_wave_barrier();
      float acc = 0.f;
      const float4* h4 = (const float4*)hbuf[wv];
      #pragma unroll
      for (int c4 = 0; c4 < 16; c4++) {
        float4 hv = h4[c4];                  // broadcast read (all lanes same addr)
        acc = fmaf(w1r[4 * c4 + 0], hv.x, acc);
        acc = fmaf(w1r[4 * c4 + 1], hv.y, acc);
        acc = fmaf(w1r[4 * c4 + 2], hv.z, acc);
        acc = fmaf(w1r[4 * c4 + 3], hv.w, acc);
      }
      __builtin_amdgcn_wave_barrier();
      s2 += acc; sq2 = fmaf(acc, acc, sq2);
      mx = fmaxf(mx, acc); mn = fminf(mn, acc);
    }
    maxb[P * 64 + lane] = mx;
    minb[P * 64 + lane] = mn;
  }
  psum[lane * 8192 + wgid] = s2;             // stat-major partials [128][8192]
  psum[(64 + lane) * 8192 + wgid] = sq2;
}

// ---------------- K4b: reduce stats2 partials (128 blocks, one per stat) ----------------
__global__ __launch_bounds__(256) void k4b_red(const float* __restrict__ psum, float* __restrict__ s2) {
  int c = blockIdx.x;
  const float* p = psum + c * 8192;
  float s = 0.f;
  for (int i = threadIdx.x; i < 8192; i += 256) s += p[i];
  for (int off = 32; off > 0; off >>= 1) s += __shfl_down(s, off);
  __shared__ float red[4];
  if ((threadIdx.x & 63) == 0) red[threadIdx.x >> 6] = s;
  __syncthreads();
  if (threadIdx.x == 0) s2[c] = red[0] + red[1] + red[2] + red[3];
}

// ---------------- K5: BN2+LReLU epilogue with LDS transpose ----------------
__global__ __launch_bounds__(256) void k5_out(const float* __restrict__ maxb, const float* __restrict__ minb,
                                              const float* __restrict__ s2, const float* __restrict__ g1,
                                              const float* __restrict__ b1, float* __restrict__ out) {
  __shared__ float T[64][65];
  __shared__ float a2s[64], b2s[64];
  int blk = blockIdx.x;
  int b = blk >> 6;
  int n0 = (blk & 63) << 6;
  int t = threadIdx.x;
  if (t < 64) {
    float mean = s2[t] * INV_M;
    float var = s2[64 + t] * INV_M - mean * mean;
    float a = g1[t] * rsqrtf(var + BN_EPS);
    a2s[t] = a;
    b2s[t] = b1[t] - mean * a;
  }
  __syncthreads();
  #pragma unroll
  for (int i = 0; i < 16; i++) {
    int lin = i * 256 + t;
    int r = lin >> 6;      // n offset within tile
    int c = lin & 63;      // channel
    float a = a2s[c];
    int P = (b << 12) + n0 + r;
    float v = (a >= 0.f) ? maxb[P * 64 + c] : minb[P * 64 + c];  // monotonicity trick
    float z = a * v + b2s[c];
    T[c][r] = z >= 0.f ? z : NEG_SLOPE * z;
  }
  __syncthreads();
  #pragma unroll
  for (int i = 0; i < 16; i++) {
    int lin = i * 256 + t;
    int c = lin >> 6;
    int nn = lin & 63;
    out[(b * 64 + c) * 4096 + n0 + nn] = T[c][nn];
  }
}

extern "C" void kernel_launch(void* const* d_in, const int* in_sizes, int n_in,
                              void* d_out, int out_size, void* d_ws, size_t ws_size,
                              hipStream_t stream) {
  const float* x  = (const float*)d_in[0];
  const float* W0 = (const float*)d_in[1];
  const float* g0 = (const float*)d_in[2];
  const float* b0 = (const float*)d_in[3];
  const float* W1 = (const float*)d_in[4];
  const float* g1 = (const float*)d_in[5];
  const float* b1 = (const float*)d_in[6];
  float* out = (float*)d_out;
  char* ws = (char*)d_ws;

  // ws layout (bytes)
  int*   idx  = (int*)(ws + 0);                              // 5,242,880 B
  float* stat = (float*)(ws + 5242880);                      // 27 floats (zeroed)
  float* a1   = (float*)(ws + 5242880 + 512);                // 64 floats
  float* b1e  = (float*)(ws + 5242880 + 768);                // 64 floats
  float* s2   = (float*)(ws + 5242880 + 1024);               // 128 floats
  float* part = (float*)(ws + 5242880 + 1536);               // 4 MB: [128][8192]
  float* maxb = (float*)(ws + 5242880 + 1536 + 4194304);     // 16 MB
  float* minb = maxb + 4194304;                              // 16 MB

  (void)hipMemsetAsync(stat, 0, 128, stream);
  k1_knn    <<<512, 1024, 0, stream>>>(x, idx);
  k2_moments<<<1024, 256, 0, stream>>>(x, idx, stat);
  k3_fin1   <<<1, 64, 0, stream>>>(stat, W0, g0, b0, a1, b1e);
  k4_main   <<<2048, 256, 0, stream>>>(x, idx, W0, W1, a1, b1e, part, maxb, minb);
  k4b_red   <<<128, 256, 0, stream>>>(part, s2);
  k5_out    <<<1024, 256, 0, stream>>>(maxb, minb, s2, g1, b1, out);
}

// Round 11
// 546.255 us; speedup vs baseline: 2.6852x; 1.3277x over previous
//
#include <hip/hip_runtime.h>
#include <cfloat>

#define NEG_SLOPE 0.2f
#define BN_EPS 1e-5f
#define EDGES 1310720   // 16*4096*20
#define INV_M (1.0f / 1310720.0f)

typedef short v8s __attribute__((ext_vector_type(8)));   // 8 bf16 (4 VGPRs) MFMA frag
typedef float v4f __attribute__((ext_vector_type(4)));   // 4 fp32 MFMA acc

// manual bf16 RNE pack / unpack (no header-struct dependence, deterministic)
__device__ __forceinline__ unsigned short f2bf(float f) {
  unsigned b = __float_as_uint(f);
  b += 0x7fffu + ((b >> 16) & 1u);
  return (unsigned short)(b >> 16);
}
__device__ __forceinline__ float bf2f(unsigned short s) {
  return __uint_as_float(((unsigned)s) << 16);
}

// Bit-exact replica of the numpy fp32 neg-distance. `#pragma clang fp contract(off)`
// is the ONLY reliable way to stop -ffp-contract=fast from fusing into fmas
// (rounds 3/6/7 evidence). KNN selection is the only bit-exact-critical path.
__device__ __forceinline__ float sqnorm_np(float c0, float c1, float c2) {
#pragma clang fp contract(off)
  return (c0 * c0 + c1 * c1) + c2 * c2;
}
__device__ __forceinline__ float negdist_np(float c0, float c1, float c2,
                                            float q0, float q1, float q2,
                                            float xxn, float xxm) {
#pragma clang fp contract(off)
  float inner = (c0 * q0 + c1 * q1) + c2 * q2;
  return (2.0f * inner - xxn) - xxm;
}

// pack (neg-dist value, index) into one u64 key: larger key == (higher value, then smaller index)
__device__ __forceinline__ unsigned long long packkey(float nd, int m) {
  unsigned u = __float_as_uint(nd);
  unsigned key = ((int)u < 0) ? ~u : (u | 0x80000000u);   // monotone float->uint
  return ((unsigned long long)key << 32) | (unsigned)(~m);
}

template <int PAT>
__device__ __forceinline__ unsigned long long swz64(unsigned long long v) {
  int hi = __builtin_amdgcn_ds_swizzle((int)(v >> 32), PAT);
  int lo = __builtin_amdgcn_ds_swizzle((int)(unsigned)v, PAT);
  return ((unsigned long long)(unsigned)hi << 32) | (unsigned)lo;
}
__device__ __forceinline__ unsigned long long bperm64(int addr, unsigned long long v) {
  int hi = __builtin_amdgcn_ds_bpermute(addr, (int)(v >> 32));
  int lo = __builtin_amdgcn_ds_bpermute(addr, (int)(unsigned)v);
  return ((unsigned long long)(unsigned)hi << 32) | (unsigned)lo;
}
__device__ __forceinline__ unsigned long long maxu64(unsigned long long a, unsigned long long b) {
  return a > b ? a : b;
}
__device__ __forceinline__ void ins3(unsigned long long k, unsigned long long& k0,
                                     unsigned long long& k1, unsigned long long& k2) {
  bool g0 = k > k0, g1 = k > k1, g2 = k > k2;
  unsigned long long n2 = g2 ? (g1 ? k1 : k) : k2;
  unsigned long long n1 = g1 ? (g0 ? k0 : k) : k1;
  k0 = g0 ? k : k0;
  k1 = n1; k2 = n2;
}

// ---------------- K1: KNN — unchanged from round 9 (verified, ~414 us, issue-bound) ----------------
__global__ __launch_bounds__(1024, 8) void k1_knn(const float* __restrict__ x, int* __restrict__ idxo) {
  __shared__ float xs0[4096], xs1[4096], xs2[4096];   // 48 KB
  int b   = blockIdx.x >> 5;
  int blk = blockIdx.x & 31;
  const float* xb = x + b * 12288;
  for (int i = threadIdx.x; i < 4096; i += 1024) {
    xs0[i] = xb[i];
    xs1[i] = xb[4096 + i];
    xs2[i] = xb[8192 + i];
  }
  __syncthreads();

  int wv = threadIdx.x >> 6;
  int lane = threadIdx.x & 63;
  int wave_id = blk * 16 + wv;
  int xaddr = ((lane ^ 32) << 2);

  #pragma unroll 1
  for (int p = 0; p < 4; p++) {
    int nA = wave_id * 8 + 2 * p;
    int nB = nA + 1;
    float qA0 = xs0[nA], qA1 = xs1[nA], qA2 = xs2[nA];
    float qB0 = xs0[nB], qB1 = xs1[nB], qB2 = xs2[nB];
    float xxnA = sqnorm_np(qA0, qA1, qA2);
    float xxnB = sqnorm_np(qB0, qB1, qB2);

    unsigned long long A0 = 0, A1 = 0, A2 = 0;
    unsigned long long B0 = 0, B1 = 0, B2 = 0;
    #pragma unroll 2
    for (int j = 0; j < 64; j++) {
      int m = (j << 6) + lane;
      float c0 = xs0[m], c1 = xs1[m], c2 = xs2[m];
      float xxm = sqnorm_np(c0, c1, c2);
      float ndA = negdist_np(c0, c1, c2, qA0, qA1, qA2, xxnA, xxm);
      ins3(packkey(ndA, m), A0, A1, A2);
      float ndB = negdist_np(c0, c1, c2, qB0, qB1, qB2, xxnB, xxm);
      ins3(packkey(ndB, m), B0, B1, B2);
    }

    unsigned long long remA = 0ull, remB = 0ull;
    int keepA = 0, keepB = 0;
    #pragma unroll 1
    for (int r = 0; r < 20; r++) {
      unsigned long long wA = A0, wB = B0;
      wA = maxu64(wA, swz64<0x041F>(wA)); wB = maxu64(wB, swz64<0x041F>(wB));
      wA = maxu64(wA, swz64<0x081F>(wA)); wB = maxu64(wB, swz64<0x081F>(wB));
      wA = maxu64(wA, swz64<0x101F>(wA)); wB = maxu64(wB, swz64<0x101F>(wB));
      wA = maxu64(wA, swz64<0x201F>(wA)); wB = maxu64(wB, swz64<0x201F>(wB));
      wA = maxu64(wA, swz64<0x401F>(wA)); wB = maxu64(wB, swz64<0x401F>(wB));
      wA = maxu64(wA, bperm64(xaddr, wA)); wB = maxu64(wB, bperm64(xaddr, wB));

      int mA = (int)~(unsigned)wA;
      int mB = (int)~(unsigned)wB;
      if (lane == r) { keepA = mA; keepB = mB; }

      bool ownA = ((mA & 63) == lane);
      remA |= ownA ? (1ull << (mA >> 6)) : 0ull;
      A0 = ownA ? A1 : A0;
      A1 = ownA ? A2 : A1;
      A2 = ownA ? 0ull : A2;
      if (ownA & (A0 == 0ull)) {
        #pragma unroll 1
        for (int j = 0; j < 64; j++) {
          int m = (j << 6) + lane;
          float c0 = xs0[m], c1 = xs1[m], c2 = xs2[m];
          float xxm = sqnorm_np(c0, c1, c2);
          float ndA = negdist_np(c0, c1, c2, qA0, qA1, qA2, xxnA, xxm);
          unsigned long long k = ((remA >> j) & 1ull) ? 0ull : packkey(ndA, m);
          ins3(k, A0, A1, A2);
        }
      }
      bool ownB = ((mB & 63) == lane);
      remB |= ownB ? (1ull << (mB >> 6)) : 0ull;
      B0 = ownB ? B1 : B0;
      B1 = ownB ? B2 : B1;
      B2 = ownB ? 0ull : B2;
      if (ownB & (B0 == 0ull)) {
        #pragma unroll 1
        for (int j = 0; j < 64; j++) {
          int m = (j << 6) + lane;
          float c0 = xs0[m], c1 = xs1[m], c2 = xs2[m];
          float xxm = sqnorm_np(c0, c1, c2);
          float ndB = negdist_np(c0, c1, c2, qB0, qB1, qB2, xxnB, xxm);
          unsigned long long k = ((remB >> j) & 1ull) ? 0ull : packkey(ndB, m);
          ins3(k, B0, B1, B2);
        }
      }
    }
    if (lane < 20) {
      idxo[((b << 12) + nA) * 20 + lane] = keepA;
      idxo[((b << 12) + nB) * 20 + lane] = keepB;
    }
  }
}

// ---------------- K2: edge moments (unchanged) ----------------
__global__ __launch_bounds__(256) void k2_moments(const float* __restrict__ x,
                                                  const int* __restrict__ idxi,
                                                  float* __restrict__ stat) {
  float acc[27];
  #pragma unroll
  for (int i = 0; i < 27; i++) acc[i] = 0.f;
  int stride = gridDim.x * blockDim.x;
  for (int e = blockIdx.x * blockDim.x + threadIdx.x; e < EDGES; e += stride) {
    int P = e / 20;
    int b = P >> 12;
    int n = P & 4095;
    int m = idxi[e];
    const float* xb = x + b * 12288;
    float xn0 = xb[n], xn1 = xb[4096 + n], xn2 = xb[8192 + n];
    float ev[6];
    ev[0] = xb[m] - xn0; ev[1] = xb[4096 + m] - xn1; ev[2] = xb[8192 + m] - xn2;
    ev[3] = xn0; ev[4] = xn1; ev[5] = xn2;
    int p = 6;
    #pragma unroll
    for (int i2 = 0; i2 < 6; i2++) {
      acc[i2] += ev[i2];
      #pragma unroll
      for (int j2 = i2; j2 < 6; j2++) { acc[p] = fmaf(ev[i2], ev[j2], acc[p]); p++; }
    }
  }
  #pragma unroll
  for (int i = 0; i < 27; i++) {
    float s = acc[i];
    for (int off = 32; off > 0; off >>= 1) s += __shfl_down(s, off);
    acc[i] = s;
  }
  __shared__ float red[4][27];
  int w = threadIdx.x >> 6, lane = threadIdx.x & 63;
  if (lane == 0) {
    #pragma unroll
    for (int i = 0; i < 27; i++) red[w][i] = acc[i];
  }
  __syncthreads();
  if (threadIdx.x < 27) {
    float s = red[0][threadIdx.x] + red[1][threadIdx.x] + red[2][threadIdx.x] + red[3][threadIdx.x];
    atomicAdd(&stat[threadIdx.x], s);
  }
}

// ---------------- K3: BN1 coefficients (unchanged) ----------------
__global__ void k3_fin1(const float* __restrict__ stat, const float* __restrict__ W0,
                        const float* __restrict__ g0, const float* __restrict__ b0,
                        float* __restrict__ a1o, float* __restrict__ b1o) {
  int c = threadIdx.x;
  float w[6];
  #pragma unroll
  for (int i = 0; i < 6; i++) w[i] = W0[c * 6 + i];
  float mean = 0.f;
  #pragma unroll
  for (int i = 0; i < 6; i++) mean += w[i] * stat[i];
  mean *= INV_M;
  float e2 = 0.f;
  int p = 6;
  #pragma unroll
  for (int i = 0; i < 6; i++) {
    #pragma unroll
    for (int j = i; j < 6; j++) {
      float f = w[i] * w[j] * stat[p]; p++;
      e2 += (i == j) ? f : 2.f * f;
    }
  }
  e2 *= INV_M;
  float var = e2 - mean * mean;
  float a = g0[c] * rsqrtf(var + BN_EPS);
  a1o[c] = a;
  b1o[c] = b0[c] - mean * a;
}

// ---------------- K0: precompute u,v with BN1 folded (bf16) ----------------
// h1n(n,m,c) = lrelu( u[m][c] + v[n][c] ):  u = a1*(W0a . x),  v = a1*((W0b-W0a) . x) + b1
__global__ __launch_bounds__(256) void k0_uv(const float* __restrict__ x, const float* __restrict__ W0,
                                             const float* __restrict__ a1, const float* __restrict__ b1e,
                                             unsigned short* __restrict__ u, unsigned short* __restrict__ v) {
  int gid = blockIdx.x * 256 + threadIdx.x;   // 0 .. 4194303
  int p = gid >> 6;
  int c = gid & 63;
  int b = p >> 12, n = p & 4095;
  const float* xb = x + b * 12288;
  float x0 = xb[n], x1 = xb[4096 + n], x2 = xb[8192 + n];
  float w0 = W0[c * 6], w1 = W0[c * 6 + 1], w2 = W0[c * 6 + 2];
  float w3 = W0[c * 6 + 3], w4 = W0[c * 6 + 4], w5 = W0[c * 6 + 5];
  float a = a1[c], bb = b1e[c];
  float uu = a * (w0 * x0 + w1 * x1 + w2 * x2);
  float vv = a * ((w3 - w0) * x0 + (w4 - w1) * x1 + (w5 - w2) * x2) + bb;
  u[gid] = f2bf(uu);
  v[gid] = f2bf(vv);
}

// ---------------- K4: conv2 via MFMA; per-point max/min + stats2 partials ----------------
// Wave handles 16 points (group g). Per j in [0,20): M-tile = the 16 points' j-th
// neighbors, N = 64 out-ch (4 tiles), K = 64 (2 chained mfma_16x16x32_bf16).
// NOTE (round-10 bug): idx holds WITHIN-BATCH indices [0,4096); u/v are indexed by
// GLOBAL point id -> must add batch base. Missing offset made batches 1..15 read
// batch 0's neighbors (absmax 9.09, BN2-renormalized garbage).
__global__ __launch_bounds__(256, 4) void k4_mfma(const unsigned short* __restrict__ u,
                                                  const unsigned short* __restrict__ v,
                                                  const int* __restrict__ idxi,
                                                  const float* __restrict__ W1,
                                                  float* __restrict__ psum,
                                                  unsigned short* __restrict__ maxb,
                                                  unsigned short* __restrict__ minb) {
  int lane = threadIdx.x & 63;
  int wv = threadIdx.x >> 6;
  int g = blockIdx.x * 4 + wv;          // group 0..4095
  int G = g * 16;                       // first point of group (groups never straddle batches)
  int bbase = (G >> 12) << 12;          // batch base in global point ids
  int row16 = lane & 15;
  int quad = lane >> 4;

  // B frags: B[k][n] = W1[n][k]; lane n=row16 (out-ch 16t+row16), k = quad*8+i (+32 for kh=1)
  v8s Bf[4][2];
  #pragma unroll
  for (int t = 0; t < 4; t++) {
    const float* wrow = W1 + (16 * t + row16) * 64 + quad * 8;
    #pragma unroll
    for (int kh = 0; kh < 2; kh++) {
      #pragma unroll
      for (int i = 0; i < 8; i++) Bf[t][kh][i] = (short)f2bf(wrow[kh * 32 + i]);
    }
  }
  // v for point G+row16, channels quad*8.. and +32, unpacked to f32 once
  const v8s* vrow = (const v8s*)(v + (G + row16) * 64);
  v8s vv0 = vrow[quad], vv1 = vrow[quad + 4];
  float v0f[8], v1f[8];
  #pragma unroll
  for (int i = 0; i < 8; i++) {
    v0f[i] = bf2f((unsigned short)vv0[i]);
    v1f[i] = bf2f((unsigned short)vv1[i]);
  }

  const int* ip = idxi + (G + row16) * 20;

  float mx[4][4], mn[4][4], s2a[4], sq2a[4];
  #pragma unroll
  for (int t = 0; t < 4; t++) {
    #pragma unroll
    for (int i = 0; i < 4; i++) { mx[t][i] = -FLT_MAX; mn[t][i] = FLT_MAX; }
    s2a[t] = 0.f; sq2a[t] = 0.f;
  }

  int m_next = ip[0];
  #pragma unroll 1
  for (int j = 0; j < 20; j++) {
    int m = bbase + m_next;               // GLOBAL neighbor id (the round-10 fix)
    if (j < 19) m_next = ip[j + 1];
    const v8s* urow = (const v8s*)(u + m * 64);
    v8s u0 = urow[quad], u1 = urow[quad + 4];
    v8s a0, a1f;
    #pragma unroll
    for (int i = 0; i < 8; i++) {
      float h = bf2f((unsigned short)u0[i]) + v0f[i];
      h = fmaxf(h, 0.2f * h);                 // lrelu
      a0[i] = (short)f2bf(h);
      float h2 = bf2f((unsigned short)u1[i]) + v1f[i];
      h2 = fmaxf(h2, 0.2f * h2);
      a1f[i] = (short)f2bf(h2);
    }
    #pragma unroll
    for (int t = 0; t < 4; t++) {
      v4f c = {0.f, 0.f, 0.f, 0.f};
      c = __builtin_amdgcn_mfma_f32_16x16x32_bf16(a0, Bf[t][0], c, 0, 0, 0);
      c = __builtin_amdgcn_mfma_f32_16x16x32_bf16(a1f, Bf[t][1], c, 0, 0, 0);
      #pragma unroll
      for (int i = 0; i < 4; i++) {
        float cv = c[i];
        mx[t][i] = fmaxf(mx[t][i], cv);
        mn[t][i] = fminf(mn[t][i], cv);
        s2a[t] += cv;
        sq2a[t] = fmaf(cv, cv, sq2a[t]);
      }
    }
  }
  // writeout: C elem i of tile t -> point G + quad*4 + i, channel 16t + row16
  #pragma unroll
  for (int t = 0; t < 4; t++) {
    #pragma unroll
    for (int i = 0; i < 4; i++) {
      int P = G + quad * 4 + i;
      maxb[P * 64 + 16 * t + row16] = f2bf(mx[t][i]);
      minb[P * 64 + 16 * t + row16] = f2bf(mn[t][i]);
    }
  }
  // stats: reduce the 4 lanes sharing a column
  #pragma unroll
  for (int t = 0; t < 4; t++) {
    float s = s2a[t], q = sq2a[t];
    s += __shfl_xor(s, 16); q += __shfl_xor(q, 16);
    s += __shfl_xor(s, 32); q += __shfl_xor(q, 32);
    if (quad == 0) {
      int c = 16 * t + row16;
      psum[c * 4096 + g] = s;
      psum[(64 + c) * 4096 + g] = q;
    }
  }
}

// ---------------- K4b: reduce stats2 partials (128 blocks, one per stat) ----------------
__global__ __launch_bounds__(256) void k4b_red(const float* __restrict__ psum, float* __restrict__ s2) {
  int c = blockIdx.x;
  const float* p = psum + c * 4096;
  float s = 0.f;
  for (int i = threadIdx.x; i < 4096; i += 256) s += p[i];
  for (int off = 32; off > 0; off >>= 1) s += __shfl_down(s, off);
  __shared__ float red[4];
  if ((threadIdx.x & 63) == 0) red[threadIdx.x >> 6] = s;
  __syncthreads();
  if (threadIdx.x == 0) s2[c] = red[0] + red[1] + red[2] + red[3];
}

// ---------------- K5: BN2+LReLU epilogue with LDS transpose (bf16 max/min inputs) ----------------
__global__ __launch_bounds__(256) void k5_out(const unsigned short* __restrict__ maxb,
                                              const unsigned short* __restrict__ minb,
                                              const float* __restrict__ s2, const float* __restrict__ g1,
                                              const float* __restrict__ b1, float* __restrict__ out) {
  __shared__ float T[64][65];
  __shared__ float a2s[64], b2s[64];
  int blk = blockIdx.x;
  int b = blk >> 6;
  int n0 = (blk & 63) << 6;
  int t = threadIdx.x;
  if (t < 64) {
    float mean = s2[t] * INV_M;
    float var = s2[64 + t] * INV_M - mean * mean;
    float a = g1[t] * rsqrtf(var + BN_EPS);
    a2s[t] = a;
    b2s[t] = b1[t] - mean * a;
  }
  __syncthreads();
  #pragma unroll
  for (int i = 0; i < 16; i++) {
    int lin = i * 256 + t;
    int r = lin >> 6;
    int c = lin & 63;
    float a = a2s[c];
    int P = (b << 12) + n0 + r;
    float vfp = bf2f((a >= 0.f) ? maxb[P * 64 + c] : minb[P * 64 + c]);  // monotonicity trick
    float z = a * vfp + b2s[c];
    T[c][r] = z >= 0.f ? z : NEG_SLOPE * z;
  }
  __syncthreads();
  #pragma unroll
  for (int i = 0; i < 16; i++) {
    int lin = i * 256 + t;
    int c = lin >> 6;
    int nn = lin & 63;
    out[(b * 64 + c) * 4096 + n0 + nn] = T[c][nn];
  }
}

extern "C" void kernel_launch(void* const* d_in, const int* in_sizes, int n_in,
                              void* d_out, int out_size, void* d_ws, size_t ws_size,
                              hipStream_t stream) {
  const float* x  = (const float*)d_in[0];
  const float* W0 = (const float*)d_in[1];
  const float* g0 = (const float*)d_in[2];
  const float* b0 = (const float*)d_in[3];
  const float* W1 = (const float*)d_in[4];
  const float* g1 = (const float*)d_in[5];
  const float* b1 = (const float*)d_in[6];
  float* out = (float*)d_out;
  char* ws = (char*)d_ws;

  // ws layout (bytes) — total ~40.9 MB
  int*            idx  = (int*)(ws + 0);                   // 5,242,880
  float*          stat = (float*)(ws + 5242880);           // 27 f (zeroed)
  float*          a1   = (float*)(ws + 5242880 + 512);     // 64 f
  float*          b1e  = (float*)(ws + 5242880 + 768);     // 64 f
  float*          s2   = (float*)(ws + 5242880 + 1024);    // 128 f
  float*          part = (float*)(ws + 5244416);           // [128][4096] = 2,097,152
  unsigned short* u    = (unsigned short*)(ws + 7341568);  // 8,388,608
  unsigned short* v    = (unsigned short*)(ws + 15730176); // 8,388,608
  unsigned short* maxb = (unsigned short*)(ws + 24118784); // 8,388,608
  unsigned short* minb = (unsigned short*)(ws + 32507392); // 8,388,608

  (void)hipMemsetAsync(stat, 0, 128, stream);
  k1_knn    <<<512, 1024, 0, stream>>>(x, idx);
  k2_moments<<<1024, 256, 0, stream>>>(x, idx, stat);
  k3_fin1   <<<1, 64, 0, stream>>>(stat, W0, g0, b0, a1, b1e);
  k0_uv     <<<16384, 256, 0, stream>>>(x, W0, a1, b1e, u, v);
  k4_mfma   <<<1024, 256, 0, stream>>>(u, v, idx, W1, part, maxb, minb);
  k4b_red   <<<128, 256, 0, stream>>>(part, s2);
  k5_out    <<<1024, 256, 0, stream>>>(maxb, minb, s2, g1, b1, out);
}

// Round 12
// 453.952 us; speedup vs baseline: 3.2311x; 1.2033x over previous
//
#include <hip/hip_runtime.h>
#include <cfloat>

#define NEG_SLOPE 0.2f
#define BN_EPS 1e-5f
#define EDGES 1310720   // 16*4096*20
#define INV_M (1.0f / 1310720.0f)

typedef short v8s __attribute__((ext_vector_type(8)));   // 8 bf16 (4 VGPRs) MFMA frag
typedef float v4f __attribute__((ext_vector_type(4)));   // 4 fp32 MFMA acc

// manual bf16 RNE pack / unpack
__device__ __forceinline__ unsigned short f2bf(float f) {
  unsigned b = __float_as_uint(f);
  b += 0x7fffu + ((b >> 16) & 1u);
  return (unsigned short)(b >> 16);
}
__device__ __forceinline__ float bf2f(unsigned short s) {
  return __uint_as_float(((unsigned)s) << 16);
}

// Bit-exact replica of the numpy fp32 neg-distance. `#pragma clang fp contract(off)`
// is the ONLY reliable way to stop -ffp-contract=fast from fusing into fmas
// (rounds 3/6/7 evidence). KNN selection is the only bit-exact-critical path.
// xxm may be precomputed at staging with the SAME sqnorm_np -> identical bits.
__device__ __forceinline__ float sqnorm_np(float c0, float c1, float c2) {
#pragma clang fp contract(off)
  return (c0 * c0 + c1 * c1) + c2 * c2;
}
__device__ __forceinline__ float negdist_np(float c0, float c1, float c2,
                                            float q0, float q1, float q2,
                                            float xxn, float xxm) {
#pragma clang fp contract(off)
  float inner = (c0 * q0 + c1 * q1) + c2 * q2;
  return (2.0f * inner - xxn) - xxm;
}

// monotone float->uint order key (for the butterfly only; hot loop stays f32)
__device__ __forceinline__ unsigned orderkey(float f) {
  unsigned u = __float_as_uint(f);
  return ((int)u < 0) ? ~u : (u | 0x80000000u);
}
__device__ __forceinline__ unsigned long long packvi(float v, int m) {
  return ((unsigned long long)orderkey(v) << 32) | (unsigned)(~m);
}

template <int PAT>
__device__ __forceinline__ unsigned long long swz64(unsigned long long v) {
  int hi = __builtin_amdgcn_ds_swizzle((int)(v >> 32), PAT);
  int lo = __builtin_amdgcn_ds_swizzle((int)(unsigned)v, PAT);
  return ((unsigned long long)(unsigned)hi << 32) | (unsigned)lo;
}
__device__ __forceinline__ unsigned long long bperm64(int addr, unsigned long long v) {
  int hi = __builtin_amdgcn_ds_bpermute(addr, (int)(v >> 32));
  int lo = __builtin_amdgcn_ds_bpermute(addr, (int)(unsigned)v);
  return ((unsigned long long)(unsigned)hi << 32) | (unsigned)lo;
}
__device__ __forceinline__ unsigned long long maxu64(unsigned long long a, unsigned long long b) {
  return a > b ? a : b;
}

// branchless sorted-insert into descending f32 top-3 (strict > keeps insertion
// order among equal values -> index-ascending, matching lax.top_k exactly)
__device__ __forceinline__ void ins3f(float nd, int m,
                                      float& v0, float& v1, float& v2,
                                      int& i0, int& i1, int& i2) {
  bool g0 = nd > v0, g1 = nd > v1, g2 = nd > v2;
  float nv2 = g2 ? (g1 ? v1 : nd) : v2;  int ni2 = g2 ? (g1 ? i1 : m) : i2;
  float nv1 = g1 ? (g0 ? v0 : nd) : v1;  int ni1 = g1 ? (g0 ? i0 : m) : i1;
  v0 = g0 ? nd : v0;                     i0 = g0 ? m : i0;
  v1 = nv1; i1 = ni1; v2 = nv2; i2 = ni2;
}

// ---------------- K1: KNN — wave per query pair; f32 lists + precomputed xxm ----------------
// grid: 512 blocks = 16 batches x 32 blocks; block = 16 waves; each wave: 4 query pairs.
// 64 KB LDS x 2 blocks/CU -> 32 waves/CU.
__global__ __launch_bounds__(1024, 8) void k1_knn(const float* __restrict__ x, int* __restrict__ idxo) {
  __shared__ float xs0[4096], xs1[4096], xs2[4096], xs3[4096];   // 64 KB (xs3 = ||x||^2)
  int b   = blockIdx.x >> 5;
  int blk = blockIdx.x & 31;
  const float* xb = x + b * 12288;
  for (int i = threadIdx.x; i < 4096; i += 1024) {
    float a0 = xb[i], a1 = xb[4096 + i], a2 = xb[8192 + i];
    xs0[i] = a0; xs1[i] = a1; xs2[i] = a2;
    xs3[i] = sqnorm_np(a0, a1, a2);          // same fn as reference path -> identical bits
  }
  __syncthreads();

  int wv = threadIdx.x >> 6;
  int lane = threadIdx.x & 63;
  int wave_id = blk * 16 + wv;
  int xaddr = ((lane ^ 32) << 2);

  #pragma unroll 1
  for (int p = 0; p < 4; p++) {
    int nA = wave_id * 8 + 2 * p;
    int nB = nA + 1;
    float qA0 = xs0[nA], qA1 = xs1[nA], qA2 = xs2[nA];
    float qB0 = xs0[nB], qB1 = xs1[nB], qB2 = xs2[nB];
    float xxnA = xs3[nA];
    float xxnB = xs3[nB];

    float vA0 = -FLT_MAX, vA1 = -FLT_MAX, vA2 = -FLT_MAX;
    float vB0 = -FLT_MAX, vB1 = -FLT_MAX, vB2 = -FLT_MAX;
    int   iA0 = 0x7fffffff, iA1 = 0x7fffffff, iA2 = 0x7fffffff;
    int   iB0 = 0x7fffffff, iB1 = 0x7fffffff, iB2 = 0x7fffffff;
    #pragma unroll 2
    for (int j = 0; j < 64; j++) {
      int m = (j << 6) + lane;
      float c0 = xs0[m], c1 = xs1[m], c2 = xs2[m];
      float xxm = xs3[m];
      float ndA = negdist_np(c0, c1, c2, qA0, qA1, qA2, xxnA, xxm);
      ins3f(ndA, m, vA0, vA1, vA2, iA0, iA1, iA2);
      float ndB = negdist_np(c0, c1, c2, qB0, qB1, qB2, xxnB, xxm);
      ins3f(ndB, m, vB0, vB1, vB2, iB0, iB1, iB2);
    }

    unsigned long long remA = 0ull, remB = 0ull;
    int keepA = 0, keepB = 0;
    #pragma unroll 1
    for (int r = 0; r < 20; r++) {
      unsigned long long wA = packvi(vA0, iA0);
      unsigned long long wB = packvi(vB0, iB0);
      wA = maxu64(wA, swz64<0x041F>(wA)); wB = maxu64(wB, swz64<0x041F>(wB));
      wA = maxu64(wA, swz64<0x081F>(wA)); wB = maxu64(wB, swz64<0x081F>(wB));
      wA = maxu64(wA, swz64<0x101F>(wA)); wB = maxu64(wB, swz64<0x101F>(wB));
      wA = maxu64(wA, swz64<0x201F>(wA)); wB = maxu64(wB, swz64<0x201F>(wB));
      wA = maxu64(wA, swz64<0x401F>(wA)); wB = maxu64(wB, swz64<0x401F>(wB));
      wA = maxu64(wA, bperm64(xaddr, wA)); wB = maxu64(wB, bperm64(xaddr, wB));

      int mA = (int)~(unsigned)wA;
      int mB = (int)~(unsigned)wB;
      if (lane == r) { keepA = mA; keepB = mB; }

      bool ownA = ((mA & 63) == lane);
      remA |= ownA ? (1ull << (mA >> 6)) : 0ull;
      vA0 = ownA ? vA1 : vA0;  iA0 = ownA ? iA1 : iA0;
      vA1 = ownA ? vA2 : vA1;  iA1 = ownA ? iA2 : iA1;
      vA2 = ownA ? -FLT_MAX : vA2;  iA2 = ownA ? 0x7fffffff : iA2;
      if (ownA & (vA0 == -FLT_MAX)) {        // exhausted (rare): rebuild from LDS
        #pragma unroll 1
        for (int j = 0; j < 64; j++) {
          int m = (j << 6) + lane;
          float c0 = xs0[m], c1 = xs1[m], c2 = xs2[m];
          float xxm = xs3[m];
          float ndA = negdist_np(c0, c1, c2, qA0, qA1, qA2, xxnA, xxm);
          if ((remA >> j) & 1ull) ndA = -FLT_MAX;
          ins3f(ndA, m, vA0, vA1, vA2, iA0, iA1, iA2);
        }
      }
      bool ownB = ((mB & 63) == lane);
      remB |= ownB ? (1ull << (mB >> 6)) : 0ull;
      vB0 = ownB ? vB1 : vB0;  iB0 = ownB ? iB1 : iB0;
      vB1 = ownB ? vB2 : vB1;  iB1 = ownB ? iB2 : iB1;
      vB2 = ownB ? -FLT_MAX : vB2;  iB2 = ownB ? 0x7fffffff : iB2;
      if (ownB & (vB0 == -FLT_MAX)) {
        #pragma unroll 1
        for (int j = 0; j < 64; j++) {
          int m = (j << 6) + lane;
          float c0 = xs0[m], c1 = xs1[m], c2 = xs2[m];
          float xxm = xs3[m];
          float ndB = negdist_np(c0, c1, c2, qB0, qB1, qB2, xxnB, xxm);
          if ((remB >> j) & 1ull) ndB = -FLT_MAX;
          ins3f(ndB, m, vB0, vB1, vB2, iB0, iB1, iB2);
        }
      }
    }
    if (lane < 20) {
      idxo[((b << 12) + nA) * 20 + lane] = keepA;
      idxo[((b << 12) + nB) * 20 + lane] = keepB;
    }
  }
}

// ---------------- K2: edge moments (unchanged) ----------------
__global__ __launch_bounds__(256) void k2_moments(const float* __restrict__ x,
                                                  const int* __restrict__ idxi,
                                                  float* __restrict__ stat) {
  float acc[27];
  #pragma unroll
  for (int i = 0; i < 27; i++) acc[i] = 0.f;
  int stride = gridDim.x * blockDim.x;
  for (int e = blockIdx.x * blockDim.x + threadIdx.x; e < EDGES; e += stride) {
    int P = e / 20;
    int b = P >> 12;
    int n = P & 4095;
    int m = idxi[e];
    const float* xb = x + b * 12288;
    float xn0 = xb[n], xn1 = xb[4096 + n], xn2 = xb[8192 + n];
    float ev[6];
    ev[0] = xb[m] - xn0; ev[1] = xb[4096 + m] - xn1; ev[2] = xb[8192 + m] - xn2;
    ev[3] = xn0; ev[4] = xn1; ev[5] = xn2;
    int p = 6;
    #pragma unroll
    for (int i2 = 0; i2 < 6; i2++) {
      acc[i2] += ev[i2];
      #pragma unroll
      for (int j2 = i2; j2 < 6; j2++) { acc[p] = fmaf(ev[i2], ev[j2], acc[p]); p++; }
    }
  }
  #pragma unroll
  for (int i = 0; i < 27; i++) {
    float s = acc[i];
    for (int off = 32; off > 0; off >>= 1) s += __shfl_down(s, off);
    acc[i] = s;
  }
  __shared__ float red[4][27];
  int w = threadIdx.x >> 6, lane = threadIdx.x & 63;
  if (lane == 0) {
    #pragma unroll
    for (int i = 0; i < 27; i++) red[w][i] = acc[i];
  }
  __syncthreads();
  if (threadIdx.x < 27) {
    float s = red[0][threadIdx.x] + red[1][threadIdx.x] + red[2][threadIdx.x] + red[3][threadIdx.x];
    atomicAdd(&stat[threadIdx.x], s);
  }
}

// ---------------- K3: BN1 coefficients (unchanged) ----------------
__global__ void k3_fin1(const float* __restrict__ stat, const float* __restrict__ W0,
                        const float* __restrict__ g0, const float* __restrict__ b0,
                        float* __restrict__ a1o, float* __restrict__ b1o) {
  int c = threadIdx.x;
  float w[6];
  #pragma unroll
  for (int i = 0; i < 6; i++) w[i] = W0[c * 6 + i];
  float mean = 0.f;
  #pragma unroll
  for (int i = 0; i < 6; i++) mean += w[i] * stat[i];
  mean *= INV_M;
  float e2 = 0.f;
  int p = 6;
  #pragma unroll
  for (int i = 0; i < 6; i++) {
    #pragma unroll
    for (int j = i; j < 6; j++) {
      float f = w[i] * w[j] * stat[p]; p++;
      e2 += (i == j) ? f : 2.f * f;
    }
  }
  e2 *= INV_M;
  float var = e2 - mean * mean;
  float a = g0[c] * rsqrtf(var + BN_EPS);
  a1o[c] = a;
  b1o[c] = b0[c] - mean * a;
}

// ---------------- K0: precompute u,v with BN1 folded (bf16) ----------------
__global__ __launch_bounds__(256) void k0_uv(const float* __restrict__ x, const float* __restrict__ W0,
                                             const float* __restrict__ a1, const float* __restrict__ b1e,
                                             unsigned short* __restrict__ u, unsigned short* __restrict__ v) {
  int gid = blockIdx.x * 256 + threadIdx.x;   // 0 .. 4194303
  int p = gid >> 6;
  int c = gid & 63;
  int b = p >> 12, n = p & 4095;
  const float* xb = x + b * 12288;
  float x0 = xb[n], x1 = xb[4096 + n], x2 = xb[8192 + n];
  float w0 = W0[c * 6], w1 = W0[c * 6 + 1], w2 = W0[c * 6 + 2];
  float w3 = W0[c * 6 + 3], w4 = W0[c * 6 + 4], w5 = W0[c * 6 + 5];
  float a = a1[c], bb = b1e[c];
  float uu = a * (w0 * x0 + w1 * x1 + w2 * x2);
  float vv = a * ((w3 - w0) * x0 + (w4 - w1) * x1 + (w5 - w2) * x2) + bb;
  u[gid] = f2bf(uu);
  v[gid] = f2bf(vv);
}

// ---------------- K4: conv2 via MFMA (unchanged from round 11) ----------------
__global__ __launch_bounds__(256, 4) void k4_mfma(const unsigned short* __restrict__ u,
                                                  const unsigned short* __restrict__ v,
                                                  const int* __restrict__ idxi,
                                                  const float* __restrict__ W1,
                                                  float* __restrict__ psum,
                                                  unsigned short* __restrict__ maxb,
                                                  unsigned short* __restrict__ minb) {
  int lane = threadIdx.x & 63;
  int wv = threadIdx.x >> 6;
  int g = blockIdx.x * 4 + wv;
  int G = g * 16;
  int bbase = (G >> 12) << 12;          // batch base (round-10 bug fix)
  int row16 = lane & 15;
  int quad = lane >> 4;

  v8s Bf[4][2];
  #pragma unroll
  for (int t = 0; t < 4; t++) {
    const float* wrow = W1 + (16 * t + row16) * 64 + quad * 8;
    #pragma unroll
    for (int kh = 0; kh < 2; kh++) {
      #pragma unroll
      for (int i = 0; i < 8; i++) Bf[t][kh][i] = (short)f2bf(wrow[kh * 32 + i]);
    }
  }
  const v8s* vrow = (const v8s*)(v + (G + row16) * 64);
  v8s vv0 = vrow[quad], vv1 = vrow[quad + 4];
  float v0f[8], v1f[8];
  #pragma unroll
  for (int i = 0; i < 8; i++) {
    v0f[i] = bf2f((unsigned short)vv0[i]);
    v1f[i] = bf2f((unsigned short)vv1[i]);
  }

  const int* ip = idxi + (G + row16) * 20;

  float mx[4][4], mn[4][4], s2a[4], sq2a[4];
  #pragma unroll
  for (int t = 0; t < 4; t++) {
    #pragma unroll
    for (int i = 0; i < 4; i++) { mx[t][i] = -FLT_MAX; mn[t][i] = FLT_MAX; }
    s2a[t] = 0.f; sq2a[t] = 0.f;
  }

  int m_next = ip[0];
  #pragma unroll 1
  for (int j = 0; j < 20; j++) {
    int m = bbase + m_next;
    if (j < 19) m_next = ip[j + 1];
    const v8s* urow = (const v8s*)(u + m * 64);
    v8s u0 = urow[quad], u1 = urow[quad + 4];
    v8s a0, a1f;
    #pragma unroll
    for (int i = 0; i < 8; i++) {
      float h = bf2f((unsigned short)u0[i]) + v0f[i];
      h = fmaxf(h, 0.2f * h);
      a0[i] = (short)f2bf(h);
      float h2 = bf2f((unsigned short)u1[i]) + v1f[i];
      h2 = fmaxf(h2, 0.2f * h2);
      a1f[i] = (short)f2bf(h2);
    }
    #pragma unroll
    for (int t = 0; t < 4; t++) {
      v4f c = {0.f, 0.f, 0.f, 0.f};
      c = __builtin_amdgcn_mfma_f32_16x16x32_bf16(a0, Bf[t][0], c, 0, 0, 0);
      c = __builtin_amdgcn_mfma_f32_16x16x32_bf16(a1f, Bf[t][1], c, 0, 0, 0);
      #pragma unroll
      for (int i = 0; i < 4; i++) {
        float cv = c[i];
        mx[t][i] = fmaxf(mx[t][i], cv);
        mn[t][i] = fminf(mn[t][i], cv);
        s2a[t] += cv;
        sq2a[t] = fmaf(cv, cv, sq2a[t]);
      }
    }
  }
  #pragma unroll
  for (int t = 0; t < 4; t++) {
    #pragma unroll
    for (int i = 0; i < 4; i++) {
      int P = G + quad * 4 + i;
      maxb[P * 64 + 16 * t + row16] = f2bf(mx[t][i]);
      minb[P * 64 + 16 * t + row16] = f2bf(mn[t][i]);
    }
  }
  #pragma unroll
  for (int t = 0; t < 4; t++) {
    float s = s2a[t], q = sq2a[t];
    s += __shfl_xor(s, 16); q += __shfl_xor(q, 16);
    s += __shfl_xor(s, 32); q += __shfl_xor(q, 32);
    if (quad == 0) {
      int c = 16 * t + row16;
      psum[c * 4096 + g] = s;
      psum[(64 + c) * 4096 + g] = q;
    }
  }
}

// ---------------- K4b: reduce stats2 partials ----------------
__global__ __launch_bounds__(256) void k4b_red(const float* __restrict__ psum, float* __restrict__ s2) {
  int c = blockIdx.x;
  const float* p = psum + c * 4096;
  float s = 0.f;
  for (int i = threadIdx.x; i < 4096; i += 256) s += p[i];
  for (int off = 32; off > 0; off >>= 1) s += __shfl_down(s, off);
  __shared__ float red[4];
  if ((threadIdx.x & 63) == 0) red[threadIdx.x >> 6] = s;
  __syncthreads();
  if (threadIdx.x == 0) s2[c] = red[0] + red[1] + red[2] + red[3];
}

// ---------------- K5: BN2+LReLU epilogue (unchanged) ----------------
__global__ __launch_bounds__(256) void k5_out(const unsigned short* __restrict__ maxb,
                                              const unsigned short* __restrict__ minb,
                                              const float* __restrict__ s2, const float* __restrict__ g1,
                                              const float* __restrict__ b1, float* __restrict__ out) {
  __shared__ float T[64][65];
  __shared__ float a2s[64], b2s[64];
  int blk = blockIdx.x;
  int b = blk >> 6;
  int n0 = (blk & 63) << 6;
  int t = threadIdx.x;
  if (t < 64) {
    float mean = s2[t] * INV_M;
    float var = s2[64 + t] * INV_M - mean * mean;
    float a = g1[t] * rsqrtf(var + BN_EPS);
    a2s[t] = a;
    b2s[t] = b1[t] - mean * a;
  }
  __syncthreads();
  #pragma unroll
  for (int i = 0; i < 16; i++) {
    int lin = i * 256 + t;
    int r = lin >> 6;
    int c = lin & 63;
    float a = a2s[c];
    int P = (b << 12) + n0 + r;
    float vfp = bf2f((a >= 0.f) ? maxb[P * 64 + c] : minb[P * 64 + c]);
    float z = a * vfp + b2s[c];
    T[c][r] = z >= 0.f ? z : NEG_SLOPE * z;
  }
  __syncthreads();
  #pragma unroll
  for (int i = 0; i < 16; i++) {
    int lin = i * 256 + t;
    int c = lin >> 6;
    int nn = lin & 63;
    out[(b * 64 + c) * 4096 + n0 + nn] = T[c][nn];
  }
}

extern "C" void kernel_launch(void* const* d_in, const int* in_sizes, int n_in,
                              void* d_out, int out_size, void* d_ws, size_t ws_size,
                              hipStream_t stream) {
  const float* x  = (const float*)d_in[0];
  const float* W0 = (const float*)d_in[1];
  const float* g0 = (const float*)d_in[2];
  const float* b0 = (const float*)d_in[3];
  const float* W1 = (const float*)d_in[4];
  const float* g1 = (const float*)d_in[5];
  const float* b1 = (const float*)d_in[6];
  float* out = (float*)d_out;
  char* ws = (char*)d_ws;

  // ws layout (bytes) — total ~40.9 MB
  int*            idx  = (int*)(ws + 0);                   // 5,242,880
  float*          stat = (float*)(ws + 5242880);           // 27 f (zeroed)
  float*          a1   = (float*)(ws + 5242880 + 512);     // 64 f
  float*          b1e  = (float*)(ws + 5242880 + 768);     // 64 f
  float*          s2   = (float*)(ws + 5242880 + 1024);    // 128 f
  float*          part = (float*)(ws + 5244416);           // [128][4096] = 2,097,152
  unsigned short* u    = (unsigned short*)(ws + 7341568);  // 8,388,608
  unsigned short* v    = (unsigned short*)(ws + 15730176); // 8,388,608
  unsigned short* maxb = (unsigned short*)(ws + 24118784); // 8,388,608
  unsigned short* minb = (unsigned short*)(ws + 32507392); // 8,388,608

  (void)hipMemsetAsync(stat, 0, 128, stream);
  k1_knn    <<<512, 1024, 0, stream>>>(x, idx);
  k2_moments<<<1024, 256, 0, stream>>>(x, idx, stat);
  k3_fin1   <<<1, 64, 0, stream>>>(stat, W0, g0, b0, a1, b1e);
  k0_uv     <<<16384, 256, 0, stream>>>(x, W0, a1, b1e, u, v);
  k4_mfma   <<<1024, 256, 0, stream>>>(u, v, idx, W1, part, maxb, minb);
  k4b_red   <<<128, 256, 0, stream>>>(part, s2);
  k5_out    <<<1024, 256, 0, stream>>>(maxb, minb, s2, g1, b1, out);
}